// Round 13
// baseline (310.328 us; speedup 1.0000x reference)
//
#include <hip/hip_runtime.h>

typedef unsigned short u16;
typedef unsigned int u32;
typedef float f4 __attribute__((ext_vector_type(4)));
typedef __bf16 b8 __attribute__((ext_vector_type(8)));
typedef _Float16 h4 __attribute__((ext_vector_type(4)));
typedef __fp16 hp2 __attribute__((ext_vector_type(2)));

#if __has_builtin(__builtin_amdgcn_exp2f)
#define EXP2(x) __builtin_amdgcn_exp2f(x)
#else
#define EXP2(x) exp2f(x)
#endif

__device__ __forceinline__ u16 f2bf(float f) {
  unsigned u = __float_as_uint(f);
  u += 0x7fffu + ((u >> 16) & 1u);
  return (u16)(u >> 16);
}
__device__ __forceinline__ float bf2f(u16 h) {
  return __uint_as_float(((unsigned)h) << 16);
}

// ------- fused input conversion: x fp32->bf16 + both weights fp32->bf16 transposed -------
__global__ void k_convert_all(const float* __restrict__ x,
                              const float* __restrict__ w_qkv,
                              const float* __restrict__ w_proj,
                              u16* __restrict__ xb, u16* __restrict__ wqkT,
                              u16* __restrict__ wpjT) {
  __shared__ u16 t[64][65];
  int bid = blockIdx.x;
  if (bid < 2048) {  // x convert, same layout
    int i = (bid * 256 + threadIdx.x) * 8;
    float4 a = *(const float4*)(x + i);
    float4 b = *(const float4*)(x + i + 4);
    union { u16 h[8]; uint4 v; } r;
    r.h[0] = f2bf(a.x); r.h[1] = f2bf(a.y); r.h[2] = f2bf(a.z); r.h[3] = f2bf(a.w);
    r.h[4] = f2bf(b.x); r.h[5] = f2bf(b.y); r.h[6] = f2bf(b.z); r.h[7] = f2bf(b.w);
    *(uint4*)(xb + i) = r.v;
    return;
  }
  const float* w; u16* wT; int Ncols, Krows, bx, by;
  if (bid < 2816) { int l = bid - 2048; w = w_qkv; wT = wqkT; Ncols = 3072; Krows = 1024; bx = l % 48; by = l / 48; }
  else            { int l = bid - 2816; w = w_proj; wT = wpjT; Ncols = 1024; Krows = 1024; bx = l & 15; by = l >> 4; }
  int n0 = bx * 64, k0 = by * 64;
#pragma unroll
  for (int it = 0; it < 16; ++it) {
    int e = it * 256 + threadIdx.x;
    int r = e >> 6, c = e & 63;
    t[r][c] = f2bf(w[(size_t)(k0 + r) * Ncols + n0 + c]);
  }
  __syncthreads();
#pragma unroll
  for (int it = 0; it < 4; ++it) {
    int e = it * 256 + threadIdx.x;
    int r = e >> 4, c0 = (e & 15) * 4;   // r = local n, c0 = local k base
    union { u16 h[4]; uint2 v; } pk;
    pk.h[0] = t[c0][r]; pk.h[1] = t[c0 + 1][r];
    pk.h[2] = t[c0 + 2][r]; pk.h[3] = t[c0 + 3][r];
    *(uint2*)(wT + (size_t)(n0 + r) * Krows + k0 + c0) = pk.v;
  }
}

// ------- 128x128 bf16 MFMA GEMM, double-buffered LDS, ONE barrier per K-iter -------
// QKV epilogue: fused per-head RMSNorm on q/k (+ attention scale on q),
// scatter q/k -> [BH][N][D] bf16, V -> transposed [BH][D][N] f16.
__global__ __launch_bounds__(256, 3) void k_gemm_qkv(
    const u16* __restrict__ A, const u16* __restrict__ Bt,
    const float* __restrict__ bias,
    u16* __restrict__ oq, u16* __restrict__ ok, u16* __restrict__ ov,
    const float* __restrict__ qw, const float* __restrict__ kw,
    int K) {
  __shared__ u16 lA[2][128 * 32];
  __shared__ u16 lB[2][128 * 32];
  const int tid = threadIdx.x;
  const int lane = tid & 63, lrow = lane & 15, lq = lane >> 4;
  const int wave = tid >> 6;
  const int bm = blockIdx.y * 128, bn = blockIdx.x * 128;
  const int wm = (wave >> 1) * 64, wn = (wave & 1) * 64;

  const int ch0 = tid, ch1 = 256 + tid;
  const u16* ap0 = A + (size_t)(bm + (ch0 >> 2)) * K + (ch0 & 3) * 8;
  const u16* ap1 = A + (size_t)(bm + (ch1 >> 2)) * K + (ch1 & 3) * 8;
  const u16* bp0 = Bt + (size_t)(bn + (ch0 >> 2)) * K + (ch0 & 3) * 8;
  const u16* bp1 = Bt + (size_t)(bn + (ch1 >> 2)) * K + (ch1 & 3) * 8;

  uint4 pA0 = *(const uint4*)ap0, pA1 = *(const uint4*)ap1;
  uint4 pB0 = *(const uint4*)bp0, pB1 = *(const uint4*)bp1;

  f4 acc[4][4] = {};
  const int iters = K >> 5;
  for (int it = 0; it < iters; ++it) {
    const int s = it & 1;
    *(uint4*)(lA[s] + ch0 * 8) = pA0; *(uint4*)(lA[s] + ch1 * 8) = pA1;
    *(uint4*)(lB[s] + ch0 * 8) = pB0; *(uint4*)(lB[s] + ch1 * 8) = pB1;
    if (it + 1 < iters) {
      ap0 += 32; ap1 += 32; bp0 += 32; bp1 += 32;
      pA0 = *(const uint4*)ap0; pA1 = *(const uint4*)ap1;
      pB0 = *(const uint4*)bp0; pB1 = *(const uint4*)bp1;
    }
    __syncthreads();
    b8 af[4], bf[4];
#pragma unroll
    for (int i = 0; i < 4; ++i)
      af[i] = *(const b8*)(lA[s] + (wm + i * 16 + lrow) * 32 + lq * 8);
#pragma unroll
    for (int j = 0; j < 4; ++j)
      bf[j] = *(const b8*)(lB[s] + (wn + j * 16 + lrow) * 32 + lq * 8);
#pragma unroll
    for (int i = 0; i < 4; ++i)
#pragma unroll
      for (int j = 0; j < 4; ++j)
        acc[i][j] = __builtin_amdgcn_mfma_f32_16x16x32_bf16(af[i], bf[j], acc[i][j], 0, 0, 0);
  }

  float bv[4];
#pragma unroll
  for (int j = 0; j < 4; ++j) bv[j] = bias[bn + wn + j * 16 + lrow];

  const float CS = 0.125f * 1.44269504088896340736f;  // scale * log2(e), folded into q
  const int n0w = bn + wn;                 // 64-aligned: one head's D-range per wave
  const int sec = n0w >> 10;               // 0=q, 1=k, 2=v (wave-uniform)
  const int h = (n0w >> 6) & 15;
#pragma unroll
  for (int i = 0; i < 4; ++i) {
    float v[4][4];  // [j][r]
#pragma unroll
    for (int j = 0; j < 4; ++j)
#pragma unroll
      for (int r = 0; r < 4; ++r) v[j][r] = acc[i][j][r] + bv[j];
    if (sec < 2) {
      u16* dst = sec == 0 ? oq : ok;
      const float* w = sec == 0 ? qw : kw;
      float ex = sec == 0 ? CS : 1.0f;
#pragma unroll
      for (int r = 0; r < 4; ++r) {
        float ss = v[0][r] * v[0][r] + v[1][r] * v[1][r] +
                   v[2][r] * v[2][r] + v[3][r] * v[3][r];
        ss += __shfl_xor(ss, 1, 64); ss += __shfl_xor(ss, 2, 64);
        ss += __shfl_xor(ss, 4, 64); ss += __shfl_xor(ss, 8, 64);
        float sc = rsqrtf(ss * (1.0f / 64.0f) + 1e-6f) * ex;
        int m = bm + wm + i * 16 + lq * 4 + r;
        int bb = m >> 11, ns = m & 2047;
        u16* rowp = dst + ((size_t)(bb * 16 + h) * 2048 + ns) * 64;
#pragma unroll
        for (int j = 0; j < 4; ++j) {
          int d = j * 16 + lrow;
          rowp[d] = f2bf(v[j][r] * sc * w[d]);
        }
      }
    } else {
      int m0 = bm + wm + i * 16 + lq * 4;
      int bb = m0 >> 11, ns = m0 & 2047;
#pragma unroll
      for (int j = 0; j < 4; ++j) {
        int d = j * 16 + lrow;
        union { _Float16 hh[4]; uint2 u; } pk;
#pragma unroll
        for (int r = 0; r < 4; ++r) pk.hh[r] = (_Float16)v[j][r];
        *(uint2*)(ov + ((size_t)(bb * 16 + h) * 64 + d) * 2048 + ns) = pk.u;
      }
    }
  }
}

// ---- 64x128 bf16 MFMA GEMM for the out-proj, double-buffered, one barrier/iter ----
__global__ __launch_bounds__(256, 4) void k_gemm2(
    const u16* __restrict__ A, const u16* __restrict__ Bt,
    const float* __restrict__ bias, float* __restrict__ outF,
    int K, int Ncols) {
  __shared__ u16 lA[2][64 * 32];
  __shared__ u16 lB[2][128 * 32];
  const int tid = threadIdx.x;
  const int lane = tid & 63, lrow = lane & 15, lq = lane >> 4;
  const int wave = tid >> 6;
  const int bm = blockIdx.y * 64, bn = blockIdx.x * 128;
  const int wm = (wave >> 1) * 32, wn = (wave & 1) * 64;

  const int cha = tid;
  const int ch0 = tid, ch1 = 256 + tid;
  const u16* ap = A + (size_t)(bm + (cha >> 2)) * K + (cha & 3) * 8;
  const u16* bp0 = Bt + (size_t)(bn + (ch0 >> 2)) * K + (ch0 & 3) * 8;
  const u16* bp1 = Bt + (size_t)(bn + (ch1 >> 2)) * K + (ch1 & 3) * 8;

  uint4 pA = *(const uint4*)ap;
  uint4 pB0 = *(const uint4*)bp0, pB1 = *(const uint4*)bp1;

  f4 acc[2][4] = {};
  const int iters = K >> 5;
  for (int it = 0; it < iters; ++it) {
    const int s = it & 1;
    *(uint4*)(lA[s] + cha * 8) = pA;
    *(uint4*)(lB[s] + ch0 * 8) = pB0; *(uint4*)(lB[s] + ch1 * 8) = pB1;
    if (it + 1 < iters) {
      ap += 32; bp0 += 32; bp1 += 32;
      pA = *(const uint4*)ap;
      pB0 = *(const uint4*)bp0; pB1 = *(const uint4*)bp1;
    }
    __syncthreads();
    b8 af[2], bf[4];
#pragma unroll
    for (int i = 0; i < 2; ++i)
      af[i] = *(const b8*)(lA[s] + (wm + i * 16 + lrow) * 32 + lq * 8);
#pragma unroll
    for (int j = 0; j < 4; ++j)
      bf[j] = *(const b8*)(lB[s] + (wn + j * 16 + lrow) * 32 + lq * 8);
#pragma unroll
    for (int i = 0; i < 2; ++i)
#pragma unroll
      for (int j = 0; j < 4; ++j)
        acc[i][j] = __builtin_amdgcn_mfma_f32_16x16x32_bf16(af[i], bf[j], acc[i][j], 0, 0, 0);
  }
#pragma unroll
  for (int i = 0; i < 2; ++i)
#pragma unroll
    for (int j = 0; j < 4; ++j) {
      int n = bn + wn + j * 16 + lrow;
      float bv = bias[n];
#pragma unroll
      for (int r = 0; r < 4; ++r) {
        int m = bm + wm + i * 16 + lq * 4 + r;
        outF[(size_t)m * Ncols + n] = acc[i][j][r] + bv;
      }
    }
}

// -------- flash attention, S^T orientation, ZERO LDS / ZERO barriers --------
// The QK^T A-operand layout (K[key=base+lane&15][d=quad*8..+8], 16B/lane,
// 1KB/instr coalesced) is loadable DIRECTLY from global; same for V (8B/lane,
// lines reused across the kt loop). So: no staging, no ds_read, no
// __syncthreads — the serial QK->exp->PV chain overlaps next-iter loads freely,
// and same-CU waves/blocks hit L1/L2 on the shared K/V stream. 256 thr =
// 4 waves x 32 q; grid (16,32) = 512 blocks = 2/CU. 64-key loop sections keep
// regs ~150 (launch_bounds(256,2)). No-max softmax (|st|<=11.6): p = exp2(st),
// reference 0; l = 1^T.P via MFMA.
__global__ __launch_bounds__(256, 2) void k_attn(
    const u16* __restrict__ qb, const u16* __restrict__ kb,
    const u16* __restrict__ vt, u16* __restrict__ ao) {
  const int bh = blockIdx.y;
  const int q0 = blockIdx.x * 128;
  const int tid = threadIdx.x, wave = tid >> 6, lane = tid & 63;
  const int lrow = lane & 15, lq = lane >> 4;
  const int wq = wave * 32;

  // Q fragments, two 16-q groups (B-operand: n=q=lane&15, k=d=quad*8+j); CS pre-folded
  b8 qf[2][2];
#pragma unroll
  for (int g = 0; g < 2; ++g)
#pragma unroll
    for (int ks = 0; ks < 2; ++ks)
      qf[g][ks] = *(const b8*)(qb + ((size_t)bh * 2048 + q0 + wq + g * 16 + lrow) * 64 +
                               ks * 32 + lq * 8);

  f4 o[2][4] = {};     // O^T partials [g][dt]: row=d=quad*4+r, col=q=lane&15
  f4 lacc[2] = {};     // l via MFMA per group
  h4 ones;
  ones[0] = (_Float16)1.0f; ones[1] = (_Float16)1.0f;
  ones[2] = (_Float16)1.0f; ones[3] = (_Float16)1.0f;

  // per-lane fixed base pointers into K and V^T
  const u16* krow = kb + (size_t)bh * 2048 * 64 + (size_t)lrow * 64 + lq * 8;
  const u16* vrow = vt + (size_t)bh * 64 * 2048 + (size_t)lrow * 2048 + lq * 4;

  for (int kt0 = 0; kt0 < 2048; kt0 += 64) {
    // A-operand K fragments straight from global (16 rows x 64B contig per instr)
    b8 kfa[2][4];
#pragma unroll
    for (int ks = 0; ks < 2; ++ks)
#pragma unroll
      for (int kt = 0; kt < 4; ++kt)
        kfa[ks][kt] = *(const b8*)(krow + (size_t)(kt0 + kt * 16) * 64 + ks * 32);

    // ST = K·Q^T for both q groups: each kf feeds 2 MFMAs
    f4 st[2][4] = {};
#pragma unroll
    for (int ks = 0; ks < 2; ++ks)
#pragma unroll
      for (int kt = 0; kt < 4; ++kt) {
        st[0][kt] = __builtin_amdgcn_mfma_f32_16x16x32_bf16(kfa[ks][kt], qf[0][ks], st[0][kt], 0, 0, 0);
        st[1][kt] = __builtin_amdgcn_mfma_f32_16x16x32_bf16(kfa[ks][kt], qf[1][ks], st[1][kt], 0, 0, 0);
      }

    // p = exp2(st): raw v_exp_f32 (bounded inputs)
    h4 pf[2][4];
#pragma unroll
    for (int g = 0; g < 2; ++g)
#pragma unroll
      for (int kt = 0; kt < 4; ++kt) {
        union { hp2 p2[2]; h4 v; } cv;
        cv.p2[0] = __builtin_amdgcn_cvt_pkrtz(EXP2(st[g][kt][0]), EXP2(st[g][kt][1]));
        cv.p2[1] = __builtin_amdgcn_cvt_pkrtz(EXP2(st[g][kt][2]), EXP2(st[g][kt][3]));
        pf[g][kt] = cv.v;
      }

    // O^T += V^T·P^T ; l += 1^T·P^T — va straight from global, feeds 2 MFMAs
#pragma unroll
    for (int kt = 0; kt < 4; ++kt) {
      lacc[0] = __builtin_amdgcn_mfma_f32_16x16x16f16(ones, pf[0][kt], lacc[0], 0, 0, 0);
      lacc[1] = __builtin_amdgcn_mfma_f32_16x16x16f16(ones, pf[1][kt], lacc[1], 0, 0, 0);
#pragma unroll
      for (int dt = 0; dt < 4; ++dt) {
        h4 va = *(const h4*)(vrow + (size_t)dt * 16 * 2048 + kt0 + kt * 16);
        o[0][dt] = __builtin_amdgcn_mfma_f32_16x16x16f16(va, pf[0][kt], o[0][dt], 0, 0, 0);
        o[1][dt] = __builtin_amdgcn_mfma_f32_16x16x16f16(va, pf[1][kt], o[1][dt], 0, 0, 0);
      }
    }
  }

  const int bb = bh >> 4, h = bh & 15;
#pragma unroll
  for (int g = 0; g < 2; ++g) {
    float inv = 1.0f / lacc[g][0];
    int q = q0 + wq + g * 16 + lrow;
#pragma unroll
    for (int dt = 0; dt < 4; ++dt) {
      union { u16 h2[4]; uint2 v; } r;
#pragma unroll
      for (int rr = 0; rr < 4; ++rr) r.h2[rr] = f2bf(o[g][dt][rr] * inv);
      *(uint2*)(ao + ((size_t)bb * 2048 + q) * 1024 + h * 64 + dt * 16 + lq * 4) = r.v;
    }
  }
}

extern "C" void kernel_launch(void* const* d_in, const int* in_sizes, int n_in,
                              void* d_out, int out_size, void* d_ws, size_t ws_size,
                              hipStream_t stream) {
  const float* x      = (const float*)d_in[0];
  const float* w_qkv  = (const float*)d_in[1];
  const float* b_qkv  = (const float*)d_in[2];
  const float* q_w    = (const float*)d_in[3];
  const float* k_w    = (const float*)d_in[4];
  const float* w_proj = (const float*)d_in[5];
  const float* b_proj = (const float*)d_in[6];
  float* out = (float*)d_out;

  u16* xb   = (u16*)d_ws;          // 4096x1024 bf16
  u16* wqkT = xb + 4194304;        // 3072x1024 bf16
  u16* wpjT = wqkT + 3145728;      // 1024x1024 bf16
  u16* qb   = wpjT + 1048576;      // [BH][N][D] bf16 (CS-scaled)
  u16* kb   = qb + 4194304;        // [BH][N][D] bf16
  u16* vtb  = kb + 4194304;        // [BH][D][N] f16
  u16* ao   = xb;                  // attention out reuses xb

  k_convert_all<<<3072, 256, 0, stream>>>(x, w_qkv, w_proj, xb, wqkT, wpjT);
  k_gemm_qkv<<<dim3(24, 32), 256, 0, stream>>>(xb, wqkT, b_qkv, qb, kb, vtb, q_w, k_w, 1024);
  k_attn<<<dim3(16, 32), 256, 0, stream>>>(qb, kb, vtb, ao);
  k_gemm2<<<dim3(8, 64), 256, 0, stream>>>(ao, wpjT, b_proj, out, 1024, 1024);
}

// Round 14
// 197.952 us; speedup vs baseline: 1.5677x; 1.5677x over previous
//
#include <hip/hip_runtime.h>

typedef unsigned short u16;
typedef unsigned int u32;
typedef float f4 __attribute__((ext_vector_type(4)));
typedef __bf16 b8 __attribute__((ext_vector_type(8)));
typedef _Float16 h4 __attribute__((ext_vector_type(4)));
typedef __fp16 hp2 __attribute__((ext_vector_type(2)));

#if __has_builtin(__builtin_amdgcn_exp2f)
#define EXP2(x) __builtin_amdgcn_exp2f(x)
#else
#define EXP2(x) exp2f(x)
#endif

__device__ __forceinline__ u16 f2bf(float f) {
  unsigned u = __float_as_uint(f);
  u += 0x7fffu + ((u >> 16) & 1u);
  return (u16)(u >> 16);
}
__device__ __forceinline__ float bf2f(u16 h) {
  return __uint_as_float(((unsigned)h) << 16);
}

// ------- fused input conversion: x fp32->bf16 + both weights fp32->bf16 transposed -------
__global__ void k_convert_all(const float* __restrict__ x,
                              const float* __restrict__ w_qkv,
                              const float* __restrict__ w_proj,
                              u16* __restrict__ xb, u16* __restrict__ wqkT,
                              u16* __restrict__ wpjT) {
  __shared__ u16 t[64][65];
  int bid = blockIdx.x;
  if (bid < 2048) {  // x convert, same layout
    int i = (bid * 256 + threadIdx.x) * 8;
    float4 a = *(const float4*)(x + i);
    float4 b = *(const float4*)(x + i + 4);
    union { u16 h[8]; uint4 v; } r;
    r.h[0] = f2bf(a.x); r.h[1] = f2bf(a.y); r.h[2] = f2bf(a.z); r.h[3] = f2bf(a.w);
    r.h[4] = f2bf(b.x); r.h[5] = f2bf(b.y); r.h[6] = f2bf(b.z); r.h[7] = f2bf(b.w);
    *(uint4*)(xb + i) = r.v;
    return;
  }
  const float* w; u16* wT; int Ncols, Krows, bx, by;
  if (bid < 2816) { int l = bid - 2048; w = w_qkv; wT = wqkT; Ncols = 3072; Krows = 1024; bx = l % 48; by = l / 48; }
  else            { int l = bid - 2816; w = w_proj; wT = wpjT; Ncols = 1024; Krows = 1024; bx = l & 15; by = l >> 4; }
  int n0 = bx * 64, k0 = by * 64;
#pragma unroll
  for (int it = 0; it < 16; ++it) {
    int e = it * 256 + threadIdx.x;
    int r = e >> 6, c = e & 63;
    t[r][c] = f2bf(w[(size_t)(k0 + r) * Ncols + n0 + c]);
  }
  __syncthreads();
#pragma unroll
  for (int it = 0; it < 4; ++it) {
    int e = it * 256 + threadIdx.x;
    int r = e >> 4, c0 = (e & 15) * 4;   // r = local n, c0 = local k base
    union { u16 h[4]; uint2 v; } pk;
    pk.h[0] = t[c0][r]; pk.h[1] = t[c0 + 1][r];
    pk.h[2] = t[c0 + 2][r]; pk.h[3] = t[c0 + 3][r];
    *(uint2*)(wT + (size_t)(n0 + r) * Krows + k0 + c0) = pk.v;
  }
}

// ------- 128x128 bf16 MFMA GEMM, double-buffered LDS, ONE barrier per K-iter -------
// QKV epilogue: fused per-head RMSNorm on q/k (+ attention scale on q),
// scatter q/k -> [BH][N][D] bf16, V -> transposed [BH][D][N] f16.
__global__ __launch_bounds__(256, 3) void k_gemm_qkv(
    const u16* __restrict__ A, const u16* __restrict__ Bt,
    const float* __restrict__ bias,
    u16* __restrict__ oq, u16* __restrict__ ok, u16* __restrict__ ov,
    const float* __restrict__ qw, const float* __restrict__ kw,
    int K) {
  __shared__ u16 lA[2][128 * 32];
  __shared__ u16 lB[2][128 * 32];
  const int tid = threadIdx.x;
  const int lane = tid & 63, lrow = lane & 15, lq = lane >> 4;
  const int wave = tid >> 6;
  const int bm = blockIdx.y * 128, bn = blockIdx.x * 128;
  const int wm = (wave >> 1) * 64, wn = (wave & 1) * 64;

  const int ch0 = tid, ch1 = 256 + tid;
  const u16* ap0 = A + (size_t)(bm + (ch0 >> 2)) * K + (ch0 & 3) * 8;
  const u16* ap1 = A + (size_t)(bm + (ch1 >> 2)) * K + (ch1 & 3) * 8;
  const u16* bp0 = Bt + (size_t)(bn + (ch0 >> 2)) * K + (ch0 & 3) * 8;
  const u16* bp1 = Bt + (size_t)(bn + (ch1 >> 2)) * K + (ch1 & 3) * 8;

  uint4 pA0 = *(const uint4*)ap0, pA1 = *(const uint4*)ap1;
  uint4 pB0 = *(const uint4*)bp0, pB1 = *(const uint4*)bp1;

  f4 acc[4][4] = {};
  const int iters = K >> 5;
  for (int it = 0; it < iters; ++it) {
    const int s = it & 1;
    *(uint4*)(lA[s] + ch0 * 8) = pA0; *(uint4*)(lA[s] + ch1 * 8) = pA1;
    *(uint4*)(lB[s] + ch0 * 8) = pB0; *(uint4*)(lB[s] + ch1 * 8) = pB1;
    if (it + 1 < iters) {
      ap0 += 32; ap1 += 32; bp0 += 32; bp1 += 32;
      pA0 = *(const uint4*)ap0; pA1 = *(const uint4*)ap1;
      pB0 = *(const uint4*)bp0; pB1 = *(const uint4*)bp1;
    }
    __syncthreads();
    b8 af[4], bf[4];
#pragma unroll
    for (int i = 0; i < 4; ++i)
      af[i] = *(const b8*)(lA[s] + (wm + i * 16 + lrow) * 32 + lq * 8);
#pragma unroll
    for (int j = 0; j < 4; ++j)
      bf[j] = *(const b8*)(lB[s] + (wn + j * 16 + lrow) * 32 + lq * 8);
#pragma unroll
    for (int i = 0; i < 4; ++i)
#pragma unroll
      for (int j = 0; j < 4; ++j)
        acc[i][j] = __builtin_amdgcn_mfma_f32_16x16x32_bf16(af[i], bf[j], acc[i][j], 0, 0, 0);
  }

  float bv[4];
#pragma unroll
  for (int j = 0; j < 4; ++j) bv[j] = bias[bn + wn + j * 16 + lrow];

  const float CS = 0.125f * 1.44269504088896340736f;  // scale * log2(e), folded into q
  const int n0w = bn + wn;                 // 64-aligned: one head's D-range per wave
  const int sec = n0w >> 10;               // 0=q, 1=k, 2=v (wave-uniform)
  const int h = (n0w >> 6) & 15;
#pragma unroll
  for (int i = 0; i < 4; ++i) {
    float v[4][4];  // [j][r]
#pragma unroll
    for (int j = 0; j < 4; ++j)
#pragma unroll
      for (int r = 0; r < 4; ++r) v[j][r] = acc[i][j][r] + bv[j];
    if (sec < 2) {
      u16* dst = sec == 0 ? oq : ok;
      const float* w = sec == 0 ? qw : kw;
      float ex = sec == 0 ? CS : 1.0f;
#pragma unroll
      for (int r = 0; r < 4; ++r) {
        float ss = v[0][r] * v[0][r] + v[1][r] * v[1][r] +
                   v[2][r] * v[2][r] + v[3][r] * v[3][r];
        ss += __shfl_xor(ss, 1, 64); ss += __shfl_xor(ss, 2, 64);
        ss += __shfl_xor(ss, 4, 64); ss += __shfl_xor(ss, 8, 64);
        float sc = rsqrtf(ss * (1.0f / 64.0f) + 1e-6f) * ex;
        int m = bm + wm + i * 16 + lq * 4 + r;
        int bb = m >> 11, ns = m & 2047;
        u16* rowp = dst + ((size_t)(bb * 16 + h) * 2048 + ns) * 64;
#pragma unroll
        for (int j = 0; j < 4; ++j) {
          int d = j * 16 + lrow;
          rowp[d] = f2bf(v[j][r] * sc * w[d]);
        }
      }
    } else {
      int m0 = bm + wm + i * 16 + lq * 4;
      int bb = m0 >> 11, ns = m0 & 2047;
#pragma unroll
      for (int j = 0; j < 4; ++j) {
        int d = j * 16 + lrow;
        union { _Float16 hh[4]; uint2 u; } pk;
#pragma unroll
        for (int r = 0; r < 4; ++r) pk.hh[r] = (_Float16)v[j][r];
        *(uint2*)(ov + ((size_t)(bb * 16 + h) * 64 + d) * 2048 + ns) = pk.u;
      }
    }
  }
}

// ---- 64x128 bf16 MFMA GEMM for the out-proj, double-buffered, one barrier/iter ----
__global__ __launch_bounds__(256, 4) void k_gemm2(
    const u16* __restrict__ A, const u16* __restrict__ Bt,
    const float* __restrict__ bias, float* __restrict__ outF,
    int K, int Ncols) {
  __shared__ u16 lA[2][64 * 32];
  __shared__ u16 lB[2][128 * 32];
  const int tid = threadIdx.x;
  const int lane = tid & 63, lrow = lane & 15, lq = lane >> 4;
  const int wave = tid >> 6;
  const int bm = blockIdx.y * 64, bn = blockIdx.x * 128;
  const int wm = (wave >> 1) * 32, wn = (wave & 1) * 64;

  const int cha = tid;
  const int ch0 = tid, ch1 = 256 + tid;
  const u16* ap = A + (size_t)(bm + (cha >> 2)) * K + (cha & 3) * 8;
  const u16* bp0 = Bt + (size_t)(bn + (ch0 >> 2)) * K + (ch0 & 3) * 8;
  const u16* bp1 = Bt + (size_t)(bn + (ch1 >> 2)) * K + (ch1 & 3) * 8;

  uint4 pA = *(const uint4*)ap;
  uint4 pB0 = *(const uint4*)bp0, pB1 = *(const uint4*)bp1;

  f4 acc[2][4] = {};
  const int iters = K >> 5;
  for (int it = 0; it < iters; ++it) {
    const int s = it & 1;
    *(uint4*)(lA[s] + cha * 8) = pA;
    *(uint4*)(lB[s] + ch0 * 8) = pB0; *(uint4*)(lB[s] + ch1 * 8) = pB1;
    if (it + 1 < iters) {
      ap += 32; bp0 += 32; bp1 += 32;
      pA = *(const uint4*)ap;
      pB0 = *(const uint4*)bp0; pB1 = *(const uint4*)bp1;
    }
    __syncthreads();
    b8 af[2], bf[4];
#pragma unroll
    for (int i = 0; i < 2; ++i)
      af[i] = *(const b8*)(lA[s] + (wm + i * 16 + lrow) * 32 + lq * 8);
#pragma unroll
    for (int j = 0; j < 4; ++j)
      bf[j] = *(const b8*)(lB[s] + (wn + j * 16 + lrow) * 32 + lq * 8);
#pragma unroll
    for (int i = 0; i < 2; ++i)
#pragma unroll
      for (int j = 0; j < 4; ++j)
        acc[i][j] = __builtin_amdgcn_mfma_f32_16x16x32_bf16(af[i], bf[j], acc[i][j], 0, 0, 0);
  }
#pragma unroll
  for (int i = 0; i < 2; ++i)
#pragma unroll
    for (int j = 0; j < 4; ++j) {
      int n = bn + wn + j * 16 + lrow;
      float bv = bias[n];
#pragma unroll
      for (int r = 0; r < 4; ++r) {
        int m = bm + wm + i * 16 + lq * 4 + r;
        outF[(size_t)m * Ncols + n] = acc[i][j][r] + bv;
      }
    }
}

// -------- flash attention, S^T orientation, dual-q, 256-thr blocks (2/CU) --------
// R12 compute structure (32 q per wave: each kf/va LDS read feeds 2 MFMAs) in
// 4-wave blocks: barriers rendezvous 4 waves instead of 8, and 2 independent
// blocks/CU overlap each other's barrier-drains (m114 co-scheduling). Staging:
// 8 chunks/thread via 2 base pointers + constant offsets. R8-proven 2-sync
// register-prefetch. No-max softmax (|st|<=11.6): p = exp2(st), reference 0;
// l = 1^T.P via MFMA.
__global__ __launch_bounds__(256, 2) void k_attn(
    const u16* __restrict__ qb, const u16* __restrict__ kb,
    const u16* __restrict__ vt, u16* __restrict__ ao) {
  __shared__ u16 lK[128 * 72];    // [key][d] bf16, stride 72 (9x16B: conflict-free)
  __shared__ u16 lV[64 * 140];    // [d][key] f16, stride 140 (35 8B-granules, odd)
  const int bh = blockIdx.y;
  const int q0 = blockIdx.x * 128;
  const int tid = threadIdx.x, wave = tid >> 6, lane = tid & 63;
  const int lrow = lane & 15, lq = lane >> 4;
  const int wq = wave * 32;

  // Q fragments, two 16-q groups (B-operand: n=q=lane&15, k=d=quad*8+j); CS pre-folded
  b8 qf[2][2];
#pragma unroll
  for (int g = 0; g < 2; ++g)
#pragma unroll
    for (int ks = 0; ks < 2; ++ks)
      qf[g][ks] = *(const b8*)(qb + ((size_t)bh * 2048 + q0 + wq + g * 16 + lrow) * 64 +
                               ks * 32 + lq * 8);

  f4 o[2][4] = {};     // O^T partials [g][dt]: row=d=quad*4+r, col=q=lane&15
  f4 lacc[2] = {};     // l via MFMA per group
  h4 ones;
  ones[0] = (_Float16)1.0f; ones[1] = (_Float16)1.0f;
  ones[2] = (_Float16)1.0f; ones[3] = (_Float16)1.0f;

  // staging: K tile 128x64 = 1024 16B-chunks (thread: rows tid>>3 + s*32),
  //          V tile 64x128 = 1024 chunks (thread: rows tid>>4 + s*16); 8/thread
  const u16* kp = kb + (size_t)bh * 2048 * 64 + (size_t)(tid >> 3) * 64 + (tid & 7) * 8;
  const u16* vp = vt + (size_t)bh * 64 * 2048 + (size_t)(tid >> 4) * 2048 + (tid & 15) * 8;
  u16* lKw = lK + (tid >> 3) * 72 + (tid & 7) * 8;
  u16* lVw = lV + (tid >> 4) * 140 + (tid & 15) * 8;

  uint4 pK[4], pV[4];
#pragma unroll
  for (int s = 0; s < 4; ++s) {
    pK[s] = *(const uint4*)(kp + s * 32 * 64);
    pV[s] = *(const uint4*)(vp + (size_t)s * 16 * 2048);
  }

  for (int it = 0; it < 16; ++it) {
    // store prefetched tile regs -> LDS (vmcnt drain overlapped prior compute)
#pragma unroll
    for (int s = 0; s < 4; ++s) {
      *(uint4*)(lKw + s * 32 * 72) = pK[s];
      *(uint2*)(lVw + s * 16 * 140) = make_uint2(pV[s].x, pV[s].y);   // 280B rows not 16B-aligned
      *(uint2*)(lVw + s * 16 * 140 + 4) = make_uint2(pV[s].z, pV[s].w);
    }
    __syncthreads();

    // issue next tile's global loads; they drain during the compute below
    if (it < 15) {
      kp += 128 * 64; vp += 128;
#pragma unroll
      for (int s = 0; s < 4; ++s) {
        pK[s] = *(const uint4*)(kp + s * 32 * 64);
        pV[s] = *(const uint4*)(vp + (size_t)s * 16 * 2048);
      }
    }

    // ST = K·Q^T for both q groups: each kf read feeds 2 MFMAs
    f4 st[2][8] = {};
#pragma unroll
    for (int ks = 0; ks < 2; ++ks)
#pragma unroll
      for (int kt = 0; kt < 8; ++kt) {
        b8 kf = *(const b8*)(lK + (kt * 16 + lrow) * 72 + ks * 32 + lq * 8);
        st[0][kt] = __builtin_amdgcn_mfma_f32_16x16x32_bf16(kf, qf[0][ks], st[0][kt], 0, 0, 0);
        st[1][kt] = __builtin_amdgcn_mfma_f32_16x16x32_bf16(kf, qf[1][ks], st[1][kt], 0, 0, 0);
      }

    // p = exp2(st): raw v_exp_f32 (bounded inputs)
    h4 pf[2][8];
#pragma unroll
    for (int g = 0; g < 2; ++g)
#pragma unroll
      for (int kt = 0; kt < 8; ++kt) {
        union { hp2 p2[2]; h4 v; } cv;
        cv.p2[0] = __builtin_amdgcn_cvt_pkrtz(EXP2(st[g][kt][0]), EXP2(st[g][kt][1]));
        cv.p2[1] = __builtin_amdgcn_cvt_pkrtz(EXP2(st[g][kt][2]), EXP2(st[g][kt][3]));
        pf[g][kt] = cv.v;
      }

    // O^T += V^T·P^T ; l += 1^T·P^T — each va read feeds 2 MFMAs
#pragma unroll
    for (int kt = 0; kt < 8; ++kt) {
      lacc[0] = __builtin_amdgcn_mfma_f32_16x16x16f16(ones, pf[0][kt], lacc[0], 0, 0, 0);
      lacc[1] = __builtin_amdgcn_mfma_f32_16x16x16f16(ones, pf[1][kt], lacc[1], 0, 0, 0);
#pragma unroll
      for (int dt = 0; dt < 4; ++dt) {
        h4 va = *(const h4*)(lV + (dt * 16 + lrow) * 140 + kt * 16 + lq * 4);
        o[0][dt] = __builtin_amdgcn_mfma_f32_16x16x16f16(va, pf[0][kt], o[0][dt], 0, 0, 0);
        o[1][dt] = __builtin_amdgcn_mfma_f32_16x16x16f16(va, pf[1][kt], o[1][dt], 0, 0, 0);
      }
    }
    __syncthreads();
  }

  const int bb = bh >> 4, h = bh & 15;
#pragma unroll
  for (int g = 0; g < 2; ++g) {
    float inv = 1.0f / lacc[g][0];
    int q = q0 + wq + g * 16 + lrow;
#pragma unroll
    for (int dt = 0; dt < 4; ++dt) {
      union { u16 h2[4]; uint2 v; } r;
#pragma unroll
      for (int rr = 0; rr < 4; ++rr) r.h2[rr] = f2bf(o[g][dt][rr] * inv);
      *(uint2*)(ao + ((size_t)bb * 2048 + q) * 1024 + h * 64 + dt * 16 + lq * 4) = r.v;
    }
  }
}

extern "C" void kernel_launch(void* const* d_in, const int* in_sizes, int n_in,
                              void* d_out, int out_size, void* d_ws, size_t ws_size,
                              hipStream_t stream) {
  const float* x      = (const float*)d_in[0];
  const float* w_qkv  = (const float*)d_in[1];
  const float* b_qkv  = (const float*)d_in[2];
  const float* q_w    = (const float*)d_in[3];
  const float* k_w    = (const float*)d_in[4];
  const float* w_proj = (const float*)d_in[5];
  const float* b_proj = (const float*)d_in[6];
  float* out = (float*)d_out;

  u16* xb   = (u16*)d_ws;          // 4096x1024 bf16
  u16* wqkT = xb + 4194304;        // 3072x1024 bf16
  u16* wpjT = wqkT + 3145728;      // 1024x1024 bf16
  u16* qb   = wpjT + 1048576;      // [BH][N][D] bf16 (CS-scaled)
  u16* kb   = qb + 4194304;        // [BH][N][D] bf16
  u16* vtb  = kb + 4194304;        // [BH][D][N] f16
  u16* ao   = xb;                  // attention out reuses xb

  k_convert_all<<<3072, 256, 0, stream>>>(x, w_qkv, w_proj, xb, wqkT, wpjT);
  k_gemm_qkv<<<dim3(24, 32), 256, 0, stream>>>(xb, wqkT, b_qkv, qb, kb, vtb, q_w, k_w, 1024);
  k_attn<<<dim3(16, 32), 256, 0, stream>>>(qb, kb, vtb, ao);
  k_gemm2<<<dim3(8, 64), 256, 0, stream>>>(ao, wpjT, b_proj, out, 1024, 1024);
}

// Round 15
// 189.589 us; speedup vs baseline: 1.6368x; 1.0441x over previous
//
#include <hip/hip_runtime.h>

typedef unsigned short u16;
typedef unsigned int u32;
typedef float f4 __attribute__((ext_vector_type(4)));
typedef __bf16 b8 __attribute__((ext_vector_type(8)));
typedef _Float16 h4 __attribute__((ext_vector_type(4)));
typedef __fp16 hp2 __attribute__((ext_vector_type(2)));

#if __has_builtin(__builtin_amdgcn_exp2f)
#define EXP2(x) __builtin_amdgcn_exp2f(x)
#else
#define EXP2(x) exp2f(x)
#endif

__device__ __forceinline__ u16 f2bf(float f) {
  unsigned u = __float_as_uint(f);
  u += 0x7fffu + ((u >> 16) & 1u);
  return (u16)(u >> 16);
}
__device__ __forceinline__ float bf2f(u16 h) {
  return __uint_as_float(((unsigned)h) << 16);
}

// ------- fused input conversion: x fp32->bf16 + both weights fp32->bf16 transposed -------
__global__ void k_convert_all(const float* __restrict__ x,
                              const float* __restrict__ w_qkv,
                              const float* __restrict__ w_proj,
                              u16* __restrict__ xb, u16* __restrict__ wqkT,
                              u16* __restrict__ wpjT) {
  __shared__ u16 t[64][65];
  int bid = blockIdx.x;
  if (bid < 2048) {  // x convert, same layout
    int i = (bid * 256 + threadIdx.x) * 8;
    float4 a = *(const float4*)(x + i);
    float4 b = *(const float4*)(x + i + 4);
    union { u16 h[8]; uint4 v; } r;
    r.h[0] = f2bf(a.x); r.h[1] = f2bf(a.y); r.h[2] = f2bf(a.z); r.h[3] = f2bf(a.w);
    r.h[4] = f2bf(b.x); r.h[5] = f2bf(b.y); r.h[6] = f2bf(b.z); r.h[7] = f2bf(b.w);
    *(uint4*)(xb + i) = r.v;
    return;
  }
  const float* w; u16* wT; int Ncols, Krows, bx, by;
  if (bid < 2816) { int l = bid - 2048; w = w_qkv; wT = wqkT; Ncols = 3072; Krows = 1024; bx = l % 48; by = l / 48; }
  else            { int l = bid - 2816; w = w_proj; wT = wpjT; Ncols = 1024; Krows = 1024; bx = l & 15; by = l >> 4; }
  int n0 = bx * 64, k0 = by * 64;
#pragma unroll
  for (int it = 0; it < 16; ++it) {
    int e = it * 256 + threadIdx.x;
    int r = e >> 6, c = e & 63;
    t[r][c] = f2bf(w[(size_t)(k0 + r) * Ncols + n0 + c]);
  }
  __syncthreads();
#pragma unroll
  for (int it = 0; it < 4; ++it) {
    int e = it * 256 + threadIdx.x;
    int r = e >> 4, c0 = (e & 15) * 4;   // r = local n, c0 = local k base
    union { u16 h[4]; uint2 v; } pk;
    pk.h[0] = t[c0][r]; pk.h[1] = t[c0 + 1][r];
    pk.h[2] = t[c0 + 2][r]; pk.h[3] = t[c0 + 3][r];
    *(uint2*)(wT + (size_t)(n0 + r) * Krows + k0 + c0) = pk.v;
  }
}

// ------- 128x128 bf16 MFMA GEMM, double-buffered LDS, ONE barrier per K-iter -------
// QKV epilogue: fused per-head RMSNorm on q/k (+ attention scale on q),
// scatter q/k -> [BH][N][D] bf16, V -> transposed [BH][D][N] f16.
__global__ __launch_bounds__(256, 3) void k_gemm_qkv(
    const u16* __restrict__ A, const u16* __restrict__ Bt,
    const float* __restrict__ bias,
    u16* __restrict__ oq, u16* __restrict__ ok, u16* __restrict__ ov,
    const float* __restrict__ qw, const float* __restrict__ kw,
    int K) {
  __shared__ u16 lA[2][128 * 32];
  __shared__ u16 lB[2][128 * 32];
  const int tid = threadIdx.x;
  const int lane = tid & 63, lrow = lane & 15, lq = lane >> 4;
  const int wave = tid >> 6;
  const int bm = blockIdx.y * 128, bn = blockIdx.x * 128;
  const int wm = (wave >> 1) * 64, wn = (wave & 1) * 64;

  const int ch0 = tid, ch1 = 256 + tid;
  const u16* ap0 = A + (size_t)(bm + (ch0 >> 2)) * K + (ch0 & 3) * 8;
  const u16* ap1 = A + (size_t)(bm + (ch1 >> 2)) * K + (ch1 & 3) * 8;
  const u16* bp0 = Bt + (size_t)(bn + (ch0 >> 2)) * K + (ch0 & 3) * 8;
  const u16* bp1 = Bt + (size_t)(bn + (ch1 >> 2)) * K + (ch1 & 3) * 8;

  uint4 pA0 = *(const uint4*)ap0, pA1 = *(const uint4*)ap1;
  uint4 pB0 = *(const uint4*)bp0, pB1 = *(const uint4*)bp1;

  f4 acc[4][4] = {};
  const int iters = K >> 5;
  for (int it = 0; it < iters; ++it) {
    const int s = it & 1;
    *(uint4*)(lA[s] + ch0 * 8) = pA0; *(uint4*)(lA[s] + ch1 * 8) = pA1;
    *(uint4*)(lB[s] + ch0 * 8) = pB0; *(uint4*)(lB[s] + ch1 * 8) = pB1;
    if (it + 1 < iters) {
      ap0 += 32; ap1 += 32; bp0 += 32; bp1 += 32;
      pA0 = *(const uint4*)ap0; pA1 = *(const uint4*)ap1;
      pB0 = *(const uint4*)bp0; pB1 = *(const uint4*)bp1;
    }
    __syncthreads();
    b8 af[4], bf[4];
#pragma unroll
    for (int i = 0; i < 4; ++i)
      af[i] = *(const b8*)(lA[s] + (wm + i * 16 + lrow) * 32 + lq * 8);
#pragma unroll
    for (int j = 0; j < 4; ++j)
      bf[j] = *(const b8*)(lB[s] + (wn + j * 16 + lrow) * 32 + lq * 8);
#pragma unroll
    for (int i = 0; i < 4; ++i)
#pragma unroll
      for (int j = 0; j < 4; ++j)
        acc[i][j] = __builtin_amdgcn_mfma_f32_16x16x32_bf16(af[i], bf[j], acc[i][j], 0, 0, 0);
  }

  float bv[4];
#pragma unroll
  for (int j = 0; j < 4; ++j) bv[j] = bias[bn + wn + j * 16 + lrow];

  const float CS = 0.125f * 1.44269504088896340736f;  // scale * log2(e), folded into q
  const int n0w = bn + wn;                 // 64-aligned: one head's D-range per wave
  const int sec = n0w >> 10;               // 0=q, 1=k, 2=v (wave-uniform)
  const int h = (n0w >> 6) & 15;
#pragma unroll
  for (int i = 0; i < 4; ++i) {
    float v[4][4];  // [j][r]
#pragma unroll
    for (int j = 0; j < 4; ++j)
#pragma unroll
      for (int r = 0; r < 4; ++r) v[j][r] = acc[i][j][r] + bv[j];
    if (sec < 2) {
      u16* dst = sec == 0 ? oq : ok;
      const float* w = sec == 0 ? qw : kw;
      float ex = sec == 0 ? CS : 1.0f;
#pragma unroll
      for (int r = 0; r < 4; ++r) {
        float ss = v[0][r] * v[0][r] + v[1][r] * v[1][r] +
                   v[2][r] * v[2][r] + v[3][r] * v[3][r];
        ss += __shfl_xor(ss, 1, 64); ss += __shfl_xor(ss, 2, 64);
        ss += __shfl_xor(ss, 4, 64); ss += __shfl_xor(ss, 8, 64);
        float sc = rsqrtf(ss * (1.0f / 64.0f) + 1e-6f) * ex;
        int m = bm + wm + i * 16 + lq * 4 + r;
        int bb = m >> 11, ns = m & 2047;
        u16* rowp = dst + ((size_t)(bb * 16 + h) * 2048 + ns) * 64;
#pragma unroll
        for (int j = 0; j < 4; ++j) {
          int d = j * 16 + lrow;
          rowp[d] = f2bf(v[j][r] * sc * w[d]);
        }
      }
    } else {
      int m0 = bm + wm + i * 16 + lq * 4;
      int bb = m0 >> 11, ns = m0 & 2047;
#pragma unroll
      for (int j = 0; j < 4; ++j) {
        int d = j * 16 + lrow;
        union { _Float16 hh[4]; uint2 u; } pk;
#pragma unroll
        for (int r = 0; r < 4; ++r) pk.hh[r] = (_Float16)v[j][r];
        *(uint2*)(ov + ((size_t)(bb * 16 + h) * 64 + d) * 2048 + ns) = pk.u;
      }
    }
  }
}

// ---- 64x128 bf16 MFMA GEMM for the out-proj, double-buffered, one barrier/iter ----
__global__ __launch_bounds__(256, 4) void k_gemm2(
    const u16* __restrict__ A, const u16* __restrict__ Bt,
    const float* __restrict__ bias, float* __restrict__ outF,
    int K, int Ncols) {
  __shared__ u16 lA[2][64 * 32];
  __shared__ u16 lB[2][128 * 32];
  const int tid = threadIdx.x;
  const int lane = tid & 63, lrow = lane & 15, lq = lane >> 4;
  const int wave = tid >> 6;
  const int bm = blockIdx.y * 64, bn = blockIdx.x * 128;
  const int wm = (wave >> 1) * 32, wn = (wave & 1) * 64;

  const int cha = tid;
  const int ch0 = tid, ch1 = 256 + tid;
  const u16* ap = A + (size_t)(bm + (cha >> 2)) * K + (cha & 3) * 8;
  const u16* bp0 = Bt + (size_t)(bn + (ch0 >> 2)) * K + (ch0 & 3) * 8;
  const u16* bp1 = Bt + (size_t)(bn + (ch1 >> 2)) * K + (ch1 & 3) * 8;

  uint4 pA = *(const uint4*)ap;
  uint4 pB0 = *(const uint4*)bp0, pB1 = *(const uint4*)bp1;

  f4 acc[2][4] = {};
  const int iters = K >> 5;
  for (int it = 0; it < iters; ++it) {
    const int s = it & 1;
    *(uint4*)(lA[s] + cha * 8) = pA;
    *(uint4*)(lB[s] + ch0 * 8) = pB0; *(uint4*)(lB[s] + ch1 * 8) = pB1;
    if (it + 1 < iters) {
      ap += 32; bp0 += 32; bp1 += 32;
      pA = *(const uint4*)ap;
      pB0 = *(const uint4*)bp0; pB1 = *(const uint4*)bp1;
    }
    __syncthreads();
    b8 af[2], bf[4];
#pragma unroll
    for (int i = 0; i < 2; ++i)
      af[i] = *(const b8*)(lA[s] + (wm + i * 16 + lrow) * 32 + lq * 8);
#pragma unroll
    for (int j = 0; j < 4; ++j)
      bf[j] = *(const b8*)(lB[s] + (wn + j * 16 + lrow) * 32 + lq * 8);
#pragma unroll
    for (int i = 0; i < 2; ++i)
#pragma unroll
      for (int j = 0; j < 4; ++j)
        acc[i][j] = __builtin_amdgcn_mfma_f32_16x16x32_bf16(af[i], bf[j], acc[i][j], 0, 0, 0);
  }
#pragma unroll
  for (int i = 0; i < 2; ++i)
#pragma unroll
    for (int j = 0; j < 4; ++j) {
      int n = bn + wn + j * 16 + lrow;
      float bv = bias[n];
#pragma unroll
      for (int r = 0; r < 4; ++r) {
        int m = bm + wm + i * 16 + lq * 4 + r;
        outF[(size_t)m * Ncols + n] = acc[i][j][r] + bv;
      }
    }
}

// -------- flash attention, S^T orientation, 32 q per wave (R12 — session best) --------
// Dual q-fragments: every kf/va LDS read feeds TWO MFMAs (halves LDS traffic &
// conflicts vs 16-q). 512 thr = 8 waves x 32 q = 256-q block; grid (8,32) =
// 256 blocks; launch_bounds(512,2) => 256-VGPR budget, no spill (84 VGPR).
// R8-proven 2-sync register-prefetch staging (4 chunks/thread — more spills,
// per R9/R14). No-max softmax (||q||2=||k||2=8, w=1 => |st|<=11.6): p =
// exp2(st) raw v_exp_f32, reference 0; l = 1^T.P via MFMA (layout-proof).
__global__ __launch_bounds__(512, 2) void k_attn(
    const u16* __restrict__ qb, const u16* __restrict__ kb,
    const u16* __restrict__ vt, u16* __restrict__ ao) {
  __shared__ u16 lK[128 * 72];    // [key][d] bf16, stride 72 (9x16B: conflict-free)
  __shared__ u16 lV[64 * 140];    // [d][key] f16, stride 140 (35 8B-granules, odd)
  const int bh = blockIdx.y;
  const int q0 = blockIdx.x * 256;
  const int tid = threadIdx.x, wave = tid >> 6, lane = tid & 63;
  const int lrow = lane & 15, lq = lane >> 4;
  const int wq = wave * 32;

  // Q fragments, two 16-q groups (B-operand: n=q=lane&15, k=d=quad*8+j); CS pre-folded
  b8 qf[2][2];
#pragma unroll
  for (int g = 0; g < 2; ++g)
#pragma unroll
    for (int ks = 0; ks < 2; ++ks)
      qf[g][ks] = *(const b8*)(qb + ((size_t)bh * 2048 + q0 + wq + g * 16 + lrow) * 64 +
                               ks * 32 + lq * 8);

  f4 o[2][4] = {};     // O^T partials [g][dt]: row=d=quad*4+r, col=q=lane&15
  f4 lacc[2] = {};     // l via MFMA per group
  h4 ones;
  ones[0] = (_Float16)1.0f; ones[1] = (_Float16)1.0f;
  ones[2] = (_Float16)1.0f; ones[3] = (_Float16)1.0f;

  // staging (R8-proven): K tile 128x64 = 1024 chunks + V tile 64x128 = 1024; 4/thread
  const int ch0 = tid, ch1 = 512 + tid;
  const u16* kp0 = kb + (size_t)bh * 2048 * 64 + (size_t)(ch0 >> 3) * 64 + (ch0 & 7) * 8;
  const u16* kp1 = kb + (size_t)bh * 2048 * 64 + (size_t)(ch1 >> 3) * 64 + (ch1 & 7) * 8;
  const u16* vp0 = vt + (size_t)bh * 64 * 2048 + (size_t)(ch0 >> 4) * 2048 + (ch0 & 15) * 8;
  const u16* vp1 = vt + (size_t)bh * 64 * 2048 + (size_t)(ch1 >> 4) * 2048 + (ch1 & 15) * 8;
  u16* lKw0 = lK + (ch0 >> 3) * 72 + (ch0 & 7) * 8;
  u16* lKw1 = lK + (ch1 >> 3) * 72 + (ch1 & 7) * 8;
  u16* lVw0 = lV + (ch0 >> 4) * 140 + (ch0 & 15) * 8;
  u16* lVw1 = lV + (ch1 >> 4) * 140 + (ch1 & 15) * 8;

  uint4 pK0 = *(const uint4*)kp0, pK1 = *(const uint4*)kp1;
  uint4 pV0 = *(const uint4*)vp0, pV1 = *(const uint4*)vp1;

  for (int it = 0; it < 16; ++it) {
    // store prefetched tile regs -> LDS (vmcnt drain overlapped prior compute)
    *(uint4*)lKw0 = pK0;
    *(uint4*)lKw1 = pK1;
    *(uint2*)lVw0 = make_uint2(pV0.x, pV0.y);     // 280B rows not 16B-aligned
    *(uint2*)(lVw0 + 4) = make_uint2(pV0.z, pV0.w);
    *(uint2*)lVw1 = make_uint2(pV1.x, pV1.y);
    *(uint2*)(lVw1 + 4) = make_uint2(pV1.z, pV1.w);
    __syncthreads();

    // issue next tile's global loads; they drain during the compute below
    if (it < 15) {
      kp0 += 128 * 64; kp1 += 128 * 64; vp0 += 128; vp1 += 128;
      pK0 = *(const uint4*)kp0; pK1 = *(const uint4*)kp1;
      pV0 = *(const uint4*)vp0; pV1 = *(const uint4*)vp1;
    }

    // ST = K·Q^T for both q groups: each kf read feeds 2 MFMAs
    f4 st[2][8] = {};
#pragma unroll
    for (int ks = 0; ks < 2; ++ks)
#pragma unroll
      for (int kt = 0; kt < 8; ++kt) {
        b8 kf = *(const b8*)(lK + (kt * 16 + lrow) * 72 + ks * 32 + lq * 8);
        st[0][kt] = __builtin_amdgcn_mfma_f32_16x16x32_bf16(kf, qf[0][ks], st[0][kt], 0, 0, 0);
        st[1][kt] = __builtin_amdgcn_mfma_f32_16x16x32_bf16(kf, qf[1][ks], st[1][kt], 0, 0, 0);
      }

    // p = exp2(st): raw v_exp_f32 (bounded inputs)
    h4 pf[2][8];
#pragma unroll
    for (int g = 0; g < 2; ++g)
#pragma unroll
      for (int kt = 0; kt < 8; ++kt) {
        union { hp2 p2[2]; h4 v; } cv;
        cv.p2[0] = __builtin_amdgcn_cvt_pkrtz(EXP2(st[g][kt][0]), EXP2(st[g][kt][1]));
        cv.p2[1] = __builtin_amdgcn_cvt_pkrtz(EXP2(st[g][kt][2]), EXP2(st[g][kt][3]));
        pf[g][kt] = cv.v;
      }

    // O^T += V^T·P^T ; l += 1^T·P^T — each va read feeds 2 MFMAs
#pragma unroll
    for (int kt = 0; kt < 8; ++kt) {
      lacc[0] = __builtin_amdgcn_mfma_f32_16x16x16f16(ones, pf[0][kt], lacc[0], 0, 0, 0);
      lacc[1] = __builtin_amdgcn_mfma_f32_16x16x16f16(ones, pf[1][kt], lacc[1], 0, 0, 0);
#pragma unroll
      for (int dt = 0; dt < 4; ++dt) {
        h4 va = *(const h4*)(lV + (dt * 16 + lrow) * 140 + kt * 16 + lq * 4);
        o[0][dt] = __builtin_amdgcn_mfma_f32_16x16x16f16(va, pf[0][kt], o[0][dt], 0, 0, 0);
        o[1][dt] = __builtin_amdgcn_mfma_f32_16x16x16f16(va, pf[1][kt], o[1][dt], 0, 0, 0);
      }
    }
    __syncthreads();
  }

  const int bb = bh >> 4, h = bh & 15;
#pragma unroll
  for (int g = 0; g < 2; ++g) {
    float inv = 1.0f / lacc[g][0];
    int q = q0 + wq + g * 16 + lrow;
#pragma unroll
    for (int dt = 0; dt < 4; ++dt) {
      union { u16 h2[4]; uint2 v; } r;
#pragma unroll
      for (int rr = 0; rr < 4; ++rr) r.h2[rr] = f2bf(o[g][dt][rr] * inv);
      *(uint2*)(ao + ((size_t)bb * 2048 + q) * 1024 + h * 64 + dt * 16 + lq * 4) = r.v;
    }
  }
}

extern "C" void kernel_launch(void* const* d_in, const int* in_sizes, int n_in,
                              void* d_out, int out_size, void* d_ws, size_t ws_size,
                              hipStream_t stream) {
  const float* x      = (const float*)d_in[0];
  const float* w_qkv  = (const float*)d_in[1];
  const float* b_qkv  = (const float*)d_in[2];
  const float* q_w    = (const float*)d_in[3];
  const float* k_w    = (const float*)d_in[4];
  const float* w_proj = (const float*)d_in[5];
  const float* b_proj = (const float*)d_in[6];
  float* out = (float*)d_out;

  u16* xb   = (u16*)d_ws;          // 4096x1024 bf16
  u16* wqkT = xb + 4194304;        // 3072x1024 bf16
  u16* wpjT = wqkT + 3145728;      // 1024x1024 bf16
  u16* qb   = wpjT + 1048576;      // [BH][N][D] bf16 (CS-scaled)
  u16* kb   = qb + 4194304;        // [BH][N][D] bf16
  u16* vtb  = kb + 4194304;        // [BH][D][N] f16
  u16* ao   = xb;                  // attention out reuses xb

  k_convert_all<<<3072, 256, 0, stream>>>(x, w_qkv, w_proj, xb, wqkT, wpjT);
  k_gemm_qkv<<<dim3(24, 32), 256, 0, stream>>>(xb, wqkT, b_qkv, qb, kb, vtb, q_w, k_w, 1024);
  k_attn<<<dim3(8, 32), 512, 0, stream>>>(qb, kb, vtb, ao);
  k_gemm2<<<dim3(8, 64), 256, 0, stream>>>(ao, wpjT, b_proj, out, 1024, 1024);
}

// Round 16
// 187.748 us; speedup vs baseline: 1.6529x; 1.0098x over previous
//
#include <hip/hip_runtime.h>

typedef unsigned short u16;
typedef unsigned int u32;
typedef float f4 __attribute__((ext_vector_type(4)));
typedef __bf16 b8 __attribute__((ext_vector_type(8)));
typedef _Float16 h4 __attribute__((ext_vector_type(4)));
typedef __fp16 hp2 __attribute__((ext_vector_type(2)));

#if __has_builtin(__builtin_amdgcn_exp2f)
#define EXP2(x) __builtin_amdgcn_exp2f(x)
#else
#define EXP2(x) exp2f(x)
#endif

__device__ __forceinline__ u16 f2bf(float f) {
  unsigned u = __float_as_uint(f);
  u += 0x7fffu + ((u >> 16) & 1u);
  return (u16)(u >> 16);
}
__device__ __forceinline__ float bf2f(u16 h) {
  return __uint_as_float(((unsigned)h) << 16);
}

// ------- fused input conversion: x fp32->bf16 + both weights fp32->bf16 transposed -------
__global__ void k_convert_all(const float* __restrict__ x,
                              const float* __restrict__ w_qkv,
                              const float* __restrict__ w_proj,
                              u16* __restrict__ xb, u16* __restrict__ wqkT,
                              u16* __restrict__ wpjT) {
  __shared__ u16 t[64][65];
  int bid = blockIdx.x;
  if (bid < 2048) {  // x convert, same layout
    int i = (bid * 256 + threadIdx.x) * 8;
    float4 a = *(const float4*)(x + i);
    float4 b = *(const float4*)(x + i + 4);
    union { u16 h[8]; uint4 v; } r;
    r.h[0] = f2bf(a.x); r.h[1] = f2bf(a.y); r.h[2] = f2bf(a.z); r.h[3] = f2bf(a.w);
    r.h[4] = f2bf(b.x); r.h[5] = f2bf(b.y); r.h[6] = f2bf(b.z); r.h[7] = f2bf(b.w);
    *(uint4*)(xb + i) = r.v;
    return;
  }
  const float* w; u16* wT; int Ncols, Krows, bx, by;
  if (bid < 2816) { int l = bid - 2048; w = w_qkv; wT = wqkT; Ncols = 3072; Krows = 1024; bx = l % 48; by = l / 48; }
  else            { int l = bid - 2816; w = w_proj; wT = wpjT; Ncols = 1024; Krows = 1024; bx = l & 15; by = l >> 4; }
  int n0 = bx * 64, k0 = by * 64;
#pragma unroll
  for (int it = 0; it < 16; ++it) {
    int e = it * 256 + threadIdx.x;
    int r = e >> 6, c = e & 63;
    t[r][c] = f2bf(w[(size_t)(k0 + r) * Ncols + n0 + c]);
  }
  __syncthreads();
#pragma unroll
  for (int it = 0; it < 4; ++it) {
    int e = it * 256 + threadIdx.x;
    int r = e >> 4, c0 = (e & 15) * 4;   // r = local n, c0 = local k base
    union { u16 h[4]; uint2 v; } pk;
    pk.h[0] = t[c0][r]; pk.h[1] = t[c0 + 1][r];
    pk.h[2] = t[c0 + 2][r]; pk.h[3] = t[c0 + 3][r];
    *(uint2*)(wT + (size_t)(n0 + r) * Krows + k0 + c0) = pk.v;
  }
}

// ------- 128x128 bf16 MFMA GEMM, double-buffered LDS, ONE barrier per K-iter -------
// QKV epilogue: fused per-head RMSNorm on q/k (+ attention scale on q),
// scatter q/k -> [BH][N][D] bf16, V -> transposed [BH][D][N] f16.
__global__ __launch_bounds__(256, 3) void k_gemm_qkv(
    const u16* __restrict__ A, const u16* __restrict__ Bt,
    const float* __restrict__ bias,
    u16* __restrict__ oq, u16* __restrict__ ok, u16* __restrict__ ov,
    const float* __restrict__ qw, const float* __restrict__ kw,
    int K) {
  __shared__ u16 lA[2][128 * 32];
  __shared__ u16 lB[2][128 * 32];
  const int tid = threadIdx.x;
  const int lane = tid & 63, lrow = lane & 15, lq = lane >> 4;
  const int wave = tid >> 6;
  const int bm = blockIdx.y * 128, bn = blockIdx.x * 128;
  const int wm = (wave >> 1) * 64, wn = (wave & 1) * 64;

  const int ch0 = tid, ch1 = 256 + tid;
  const u16* ap0 = A + (size_t)(bm + (ch0 >> 2)) * K + (ch0 & 3) * 8;
  const u16* ap1 = A + (size_t)(bm + (ch1 >> 2)) * K + (ch1 & 3) * 8;
  const u16* bp0 = Bt + (size_t)(bn + (ch0 >> 2)) * K + (ch0 & 3) * 8;
  const u16* bp1 = Bt + (size_t)(bn + (ch1 >> 2)) * K + (ch1 & 3) * 8;

  uint4 pA0 = *(const uint4*)ap0, pA1 = *(const uint4*)ap1;
  uint4 pB0 = *(const uint4*)bp0, pB1 = *(const uint4*)bp1;

  f4 acc[4][4] = {};
  const int iters = K >> 5;
  for (int it = 0; it < iters; ++it) {
    const int s = it & 1;
    *(uint4*)(lA[s] + ch0 * 8) = pA0; *(uint4*)(lA[s] + ch1 * 8) = pA1;
    *(uint4*)(lB[s] + ch0 * 8) = pB0; *(uint4*)(lB[s] + ch1 * 8) = pB1;
    if (it + 1 < iters) {
      ap0 += 32; ap1 += 32; bp0 += 32; bp1 += 32;
      pA0 = *(const uint4*)ap0; pA1 = *(const uint4*)ap1;
      pB0 = *(const uint4*)bp0; pB1 = *(const uint4*)bp1;
    }
    __syncthreads();
    b8 af[4], bf[4];
#pragma unroll
    for (int i = 0; i < 4; ++i)
      af[i] = *(const b8*)(lA[s] + (wm + i * 16 + lrow) * 32 + lq * 8);
#pragma unroll
    for (int j = 0; j < 4; ++j)
      bf[j] = *(const b8*)(lB[s] + (wn + j * 16 + lrow) * 32 + lq * 8);
#pragma unroll
    for (int i = 0; i < 4; ++i)
#pragma unroll
      for (int j = 0; j < 4; ++j)
        acc[i][j] = __builtin_amdgcn_mfma_f32_16x16x32_bf16(af[i], bf[j], acc[i][j], 0, 0, 0);
  }

  float bv[4];
#pragma unroll
  for (int j = 0; j < 4; ++j) bv[j] = bias[bn + wn + j * 16 + lrow];

  const float CS = 0.125f * 1.44269504088896340736f;  // scale * log2(e), folded into q
  const int n0w = bn + wn;                 // 64-aligned: one head's D-range per wave
  const int sec = n0w >> 10;               // 0=q, 1=k, 2=v (wave-uniform)
  const int h = (n0w >> 6) & 15;
#pragma unroll
  for (int i = 0; i < 4; ++i) {
    float v[4][4];  // [j][r]
#pragma unroll
    for (int j = 0; j < 4; ++j)
#pragma unroll
      for (int r = 0; r < 4; ++r) v[j][r] = acc[i][j][r] + bv[j];
    if (sec < 2) {
      u16* dst = sec == 0 ? oq : ok;
      const float* w = sec == 0 ? qw : kw;
      float ex = sec == 0 ? CS : 1.0f;
#pragma unroll
      for (int r = 0; r < 4; ++r) {
        float ss = v[0][r] * v[0][r] + v[1][r] * v[1][r] +
                   v[2][r] * v[2][r] + v[3][r] * v[3][r];
        ss += __shfl_xor(ss, 1, 64); ss += __shfl_xor(ss, 2, 64);
        ss += __shfl_xor(ss, 4, 64); ss += __shfl_xor(ss, 8, 64);
        float sc = rsqrtf(ss * (1.0f / 64.0f) + 1e-6f) * ex;
        int m = bm + wm + i * 16 + lq * 4 + r;
        int bb = m >> 11, ns = m & 2047;
        u16* rowp = dst + ((size_t)(bb * 16 + h) * 2048 + ns) * 64;
#pragma unroll
        for (int j = 0; j < 4; ++j) {
          int d = j * 16 + lrow;
          rowp[d] = f2bf(v[j][r] * sc * w[d]);
        }
      }
    } else {
      int m0 = bm + wm + i * 16 + lq * 4;
      int bb = m0 >> 11, ns = m0 & 2047;
#pragma unroll
      for (int j = 0; j < 4; ++j) {
        int d = j * 16 + lrow;
        union { _Float16 hh[4]; uint2 u; } pk;
#pragma unroll
        for (int r = 0; r < 4; ++r) pk.hh[r] = (_Float16)v[j][r];
        *(uint2*)(ov + ((size_t)(bb * 16 + h) * 64 + d) * 2048 + ns) = pk.u;
      }
    }
  }
}

// ---- 64x128 bf16 MFMA GEMM for the out-proj, double-buffered, one barrier/iter ----
__global__ __launch_bounds__(256, 4) void k_gemm2(
    const u16* __restrict__ A, const u16* __restrict__ Bt,
    const float* __restrict__ bias, float* __restrict__ outF,
    int K, int Ncols) {
  __shared__ u16 lA[2][64 * 32];
  __shared__ u16 lB[2][128 * 32];
  const int tid = threadIdx.x;
  const int lane = tid & 63, lrow = lane & 15, lq = lane >> 4;
  const int wave = tid >> 6;
  const int bm = blockIdx.y * 64, bn = blockIdx.x * 128;
  const int wm = (wave >> 1) * 32, wn = (wave & 1) * 64;

  const int cha = tid;
  const int ch0 = tid, ch1 = 256 + tid;
  const u16* ap = A + (size_t)(bm + (cha >> 2)) * K + (cha & 3) * 8;
  const u16* bp0 = Bt + (size_t)(bn + (ch0 >> 2)) * K + (ch0 & 3) * 8;
  const u16* bp1 = Bt + (size_t)(bn + (ch1 >> 2)) * K + (ch1 & 3) * 8;

  uint4 pA = *(const uint4*)ap;
  uint4 pB0 = *(const uint4*)bp0, pB1 = *(const uint4*)bp1;

  f4 acc[2][4] = {};
  const int iters = K >> 5;
  for (int it = 0; it < iters; ++it) {
    const int s = it & 1;
    *(uint4*)(lA[s] + cha * 8) = pA;
    *(uint4*)(lB[s] + ch0 * 8) = pB0; *(uint4*)(lB[s] + ch1 * 8) = pB1;
    if (it + 1 < iters) {
      ap += 32; bp0 += 32; bp1 += 32;
      pA = *(const uint4*)ap;
      pB0 = *(const uint4*)bp0; pB1 = *(const uint4*)bp1;
    }
    __syncthreads();
    b8 af[2], bf[4];
#pragma unroll
    for (int i = 0; i < 2; ++i)
      af[i] = *(const b8*)(lA[s] + (wm + i * 16 + lrow) * 32 + lq * 8);
#pragma unroll
    for (int j = 0; j < 4; ++j)
      bf[j] = *(const b8*)(lB[s] + (wn + j * 16 + lrow) * 32 + lq * 8);
#pragma unroll
    for (int i = 0; i < 2; ++i)
#pragma unroll
      for (int j = 0; j < 4; ++j)
        acc[i][j] = __builtin_amdgcn_mfma_f32_16x16x32_bf16(af[i], bf[j], acc[i][j], 0, 0, 0);
  }
#pragma unroll
  for (int i = 0; i < 2; ++i)
#pragma unroll
    for (int j = 0; j < 4; ++j) {
      int n = bn + wn + j * 16 + lrow;
      float bv = bias[n];
#pragma unroll
      for (int r = 0; r < 4; ++r) {
        int m = bm + wm + i * 16 + lq * 4 + r;
        outF[(size_t)m * Ncols + n] = acc[i][j][r] + bv;
      }
    }
}

// -------- flash attention, S^T orientation, 32 q per wave (R12 base) --------
// R16 deltas vs R12: (1) l-reduction moved OFF the MFMA pipe (now the busier
// one at 45%) back to R5's VALU scheme: lsum f4 += e per iter, single 2-shuffle
// reduce at the end — removes 16 of 112 MFMAs/iter/wave. (2) XCD swizzle:
// 1-D grid, bh = b & 31 => the 8 q-blocks sharing one head's K/V stream are
// congruent mod 8 => same XCD => K/V served from that XCD's L2 (4 heads x
// 512KB = 2MB < 4MB L2). Everything else identical to R12 (session best).
__global__ __launch_bounds__(512, 2) void k_attn(
    const u16* __restrict__ qb, const u16* __restrict__ kb,
    const u16* __restrict__ vt, u16* __restrict__ ao) {
  __shared__ u16 lK[128 * 72];    // [key][d] bf16, stride 72 (9x16B: conflict-free)
  __shared__ u16 lV[64 * 140];    // [d][key] f16, stride 140 (35 8B-granules, odd)
  const int b = blockIdx.x;
  const int bh = b & 31;          // XCD swizzle: same-bh blocks == same id mod 8
  const int q0 = (b >> 5) * 256;
  const int tid = threadIdx.x, wave = tid >> 6, lane = tid & 63;
  const int lrow = lane & 15, lq = lane >> 4;
  const int wq = wave * 32;

  // Q fragments, two 16-q groups (B-operand: n=q=lane&15, k=d=quad*8+j); CS pre-folded
  b8 qf[2][2];
#pragma unroll
  for (int g = 0; g < 2; ++g)
#pragma unroll
    for (int ks = 0; ks < 2; ++ks)
      qf[g][ks] = *(const b8*)(qb + ((size_t)bh * 2048 + q0 + wq + g * 16 + lrow) * 64 +
                               ks * 32 + lq * 8);

  f4 o[2][4] = {};     // O^T partials [g][dt]: row=d=quad*4+r, col=q=lane&15
  f4 lsum[2] = {};     // deferred l partials (VALU; reduced once at the end)

  // staging (R8-proven): K tile 128x64 = 1024 chunks + V tile 64x128 = 1024; 4/thread
  const int ch0 = tid, ch1 = 512 + tid;
  const u16* kp0 = kb + (size_t)bh * 2048 * 64 + (size_t)(ch0 >> 3) * 64 + (ch0 & 7) * 8;
  const u16* kp1 = kb + (size_t)bh * 2048 * 64 + (size_t)(ch1 >> 3) * 64 + (ch1 & 7) * 8;
  const u16* vp0 = vt + (size_t)bh * 64 * 2048 + (size_t)(ch0 >> 4) * 2048 + (ch0 & 15) * 8;
  const u16* vp1 = vt + (size_t)bh * 64 * 2048 + (size_t)(ch1 >> 4) * 2048 + (ch1 & 15) * 8;
  u16* lKw0 = lK + (ch0 >> 3) * 72 + (ch0 & 7) * 8;
  u16* lKw1 = lK + (ch1 >> 3) * 72 + (ch1 & 7) * 8;
  u16* lVw0 = lV + (ch0 >> 4) * 140 + (ch0 & 15) * 8;
  u16* lVw1 = lV + (ch1 >> 4) * 140 + (ch1 & 15) * 8;

  uint4 pK0 = *(const uint4*)kp0, pK1 = *(const uint4*)kp1;
  uint4 pV0 = *(const uint4*)vp0, pV1 = *(const uint4*)vp1;

  for (int it = 0; it < 16; ++it) {
    // store prefetched tile regs -> LDS (vmcnt drain overlapped prior compute)
    *(uint4*)lKw0 = pK0;
    *(uint4*)lKw1 = pK1;
    *(uint2*)lVw0 = make_uint2(pV0.x, pV0.y);     // 280B rows not 16B-aligned
    *(uint2*)(lVw0 + 4) = make_uint2(pV0.z, pV0.w);
    *(uint2*)lVw1 = make_uint2(pV1.x, pV1.y);
    *(uint2*)(lVw1 + 4) = make_uint2(pV1.z, pV1.w);
    __syncthreads();

    // issue next tile's global loads; they drain during the compute below
    if (it < 15) {
      kp0 += 128 * 64; kp1 += 128 * 64; vp0 += 128; vp1 += 128;
      pK0 = *(const uint4*)kp0; pK1 = *(const uint4*)kp1;
      pV0 = *(const uint4*)vp0; pV1 = *(const uint4*)vp1;
    }

    // ST = K·Q^T for both q groups: each kf read feeds 2 MFMAs
    f4 st[2][8] = {};
#pragma unroll
    for (int ks = 0; ks < 2; ++ks)
#pragma unroll
      for (int kt = 0; kt < 8; ++kt) {
        b8 kf = *(const b8*)(lK + (kt * 16 + lrow) * 72 + ks * 32 + lq * 8);
        st[0][kt] = __builtin_amdgcn_mfma_f32_16x16x32_bf16(kf, qf[0][ks], st[0][kt], 0, 0, 0);
        st[1][kt] = __builtin_amdgcn_mfma_f32_16x16x32_bf16(kf, qf[1][ks], st[1][kt], 0, 0, 0);
      }

    // p = exp2(st): raw v_exp_f32 (bounded inputs); l accumulates on VALU
    h4 pf[2][8];
#pragma unroll
    for (int g = 0; g < 2; ++g)
#pragma unroll
      for (int kt = 0; kt < 8; ++kt) {
        f4 e;
#pragma unroll
        for (int r = 0; r < 4; ++r) e[r] = EXP2(st[g][kt][r]);
        lsum[g] += e;
        union { hp2 p2[2]; h4 v; } cv;
        cv.p2[0] = __builtin_amdgcn_cvt_pkrtz(e[0], e[1]);
        cv.p2[1] = __builtin_amdgcn_cvt_pkrtz(e[2], e[3]);
        pf[g][kt] = cv.v;
      }

    // O^T += V^T·P^T — each va read feeds 2 MFMAs
#pragma unroll
    for (int kt = 0; kt < 8; ++kt) {
#pragma unroll
      for (int dt = 0; dt < 4; ++dt) {
        h4 va = *(const h4*)(lV + (dt * 16 + lrow) * 140 + kt * 16 + lq * 4);
        o[0][dt] = __builtin_amdgcn_mfma_f32_16x16x16f16(va, pf[0][kt], o[0][dt], 0, 0, 0);
        o[1][dt] = __builtin_amdgcn_mfma_f32_16x16x16f16(va, pf[1][kt], o[1][dt], 0, 0, 0);
      }
    }
    __syncthreads();
  }

  const int bb = bh >> 4, h = bh & 15;
#pragma unroll
  for (int g = 0; g < 2; ++g) {
    // final l reduction: 4 regs + 2 shuffles across the 4 quads (R5-verified)
    float l = lsum[g][0] + lsum[g][1] + lsum[g][2] + lsum[g][3];
    l += __shfl_xor(l, 16, 64);
    l += __shfl_xor(l, 32, 64);
    float inv = 1.0f / l;
    int q = q0 + wq + g * 16 + lrow;
#pragma unroll
    for (int dt = 0; dt < 4; ++dt) {
      union { u16 h2[4]; uint2 v; } r;
#pragma unroll
      for (int rr = 0; rr < 4; ++rr) r.h2[rr] = f2bf(o[g][dt][rr] * inv);
      *(uint2*)(ao + ((size_t)bb * 2048 + q) * 1024 + h * 64 + dt * 16 + lq * 4) = r.v;
    }
  }
}

extern "C" void kernel_launch(void* const* d_in, const int* in_sizes, int n_in,
                              void* d_out, int out_size, void* d_ws, size_t ws_size,
                              hipStream_t stream) {
  const float* x      = (const float*)d_in[0];
  const float* w_qkv  = (const float*)d_in[1];
  const float* b_qkv  = (const float*)d_in[2];
  const float* q_w    = (const float*)d_in[3];
  const float* k_w    = (const float*)d_in[4];
  const float* w_proj = (const float*)d_in[5];
  const float* b_proj = (const float*)d_in[6];
  float* out = (float*)d_out;

  u16* xb   = (u16*)d_ws;          // 4096x1024 bf16
  u16* wqkT = xb + 4194304;        // 3072x1024 bf16
  u16* wpjT = wqkT + 3145728;      // 1024x1024 bf16
  u16* qb   = wpjT + 1048576;      // [BH][N][D] bf16 (CS-scaled)
  u16* kb   = qb + 4194304;        // [BH][N][D] bf16
  u16* vtb  = kb + 4194304;        // [BH][D][N] f16
  u16* ao   = xb;                  // attention out reuses xb

  k_convert_all<<<3072, 256, 0, stream>>>(x, w_qkv, w_proj, xb, wqkT, wpjT);
  k_gemm_qkv<<<dim3(24, 32), 256, 0, stream>>>(xb, wqkT, b_qkv, qb, kb, vtb, q_w, k_w, 1024);
  k_attn<<<256, 512, 0, stream>>>(qb, kb, vtb, ao);
  k_gemm2<<<dim3(8, 64), 256, 0, stream>>>(ao, wpjT, b_proj, out, 1024, 1024);
}

// Round 17
// 185.957 us; speedup vs baseline: 1.6688x; 1.0096x over previous
//
#include <hip/hip_runtime.h>

typedef unsigned short u16;
typedef unsigned int u32;
typedef float f4 __attribute__((ext_vector_type(4)));
typedef __bf16 b8 __attribute__((ext_vector_type(8)));
typedef _Float16 h4 __attribute__((ext_vector_type(4)));
typedef __fp16 hp2 __attribute__((ext_vector_type(2)));

#if __has_builtin(__builtin_amdgcn_exp2f)
#define EXP2(x) __builtin_amdgcn_exp2f(x)
#else
#define EXP2(x) exp2f(x)
#endif

__device__ __forceinline__ u16 f2bf(float f) {
  unsigned u = __float_as_uint(f);
  u += 0x7fffu + ((u >> 16) & 1u);
  return (u16)(u >> 16);
}
__device__ __forceinline__ float bf2f(u16 h) {
  return __uint_as_float(((unsigned)h) << 16);
}

// ------- fused input conversion: x fp32->bf16 + both weights fp32->bf16 transposed -------
__global__ void k_convert_all(const float* __restrict__ x,
                              const float* __restrict__ w_qkv,
                              const float* __restrict__ w_proj,
                              u16* __restrict__ xb, u16* __restrict__ wqkT,
                              u16* __restrict__ wpjT) {
  __shared__ u16 t[64][65];
  int bid = blockIdx.x;
  if (bid < 2048) {  // x convert, same layout
    int i = (bid * 256 + threadIdx.x) * 8;
    float4 a = *(const float4*)(x + i);
    float4 b = *(const float4*)(x + i + 4);
    union { u16 h[8]; uint4 v; } r;
    r.h[0] = f2bf(a.x); r.h[1] = f2bf(a.y); r.h[2] = f2bf(a.z); r.h[3] = f2bf(a.w);
    r.h[4] = f2bf(b.x); r.h[5] = f2bf(b.y); r.h[6] = f2bf(b.z); r.h[7] = f2bf(b.w);
    *(uint4*)(xb + i) = r.v;
    return;
  }
  const float* w; u16* wT; int Ncols, Krows, bx, by;
  if (bid < 2816) { int l = bid - 2048; w = w_qkv; wT = wqkT; Ncols = 3072; Krows = 1024; bx = l % 48; by = l / 48; }
  else            { int l = bid - 2816; w = w_proj; wT = wpjT; Ncols = 1024; Krows = 1024; bx = l & 15; by = l >> 4; }
  int n0 = bx * 64, k0 = by * 64;
#pragma unroll
  for (int it = 0; it < 16; ++it) {
    int e = it * 256 + threadIdx.x;
    int r = e >> 6, c = e & 63;
    t[r][c] = f2bf(w[(size_t)(k0 + r) * Ncols + n0 + c]);
  }
  __syncthreads();
#pragma unroll
  for (int it = 0; it < 4; ++it) {
    int e = it * 256 + threadIdx.x;
    int r = e >> 4, c0 = (e & 15) * 4;   // r = local n, c0 = local k base
    union { u16 h[4]; uint2 v; } pk;
    pk.h[0] = t[c0][r]; pk.h[1] = t[c0 + 1][r];
    pk.h[2] = t[c0 + 2][r]; pk.h[3] = t[c0 + 3][r];
    *(uint2*)(wT + (size_t)(n0 + r) * Krows + k0 + c0) = pk.v;
  }
}

// ------- 128x128 bf16 MFMA GEMM, double-buffered LDS, ONE barrier per K-iter -------
// QKV epilogue: fused per-head RMSNorm on q/k (+ attention scale on q),
// scatter q/k -> [BH][N][D] bf16, V -> transposed [BH][D][N] f16.
__global__ __launch_bounds__(256, 3) void k_gemm_qkv(
    const u16* __restrict__ A, const u16* __restrict__ Bt,
    const float* __restrict__ bias,
    u16* __restrict__ oq, u16* __restrict__ ok, u16* __restrict__ ov,
    const float* __restrict__ qw, const float* __restrict__ kw,
    int K) {
  __shared__ u16 lA[2][128 * 32];
  __shared__ u16 lB[2][128 * 32];
  const int tid = threadIdx.x;
  const int lane = tid & 63, lrow = lane & 15, lq = lane >> 4;
  const int wave = tid >> 6;
  const int bm = blockIdx.y * 128, bn = blockIdx.x * 128;
  const int wm = (wave >> 1) * 64, wn = (wave & 1) * 64;

  const int ch0 = tid, ch1 = 256 + tid;
  const u16* ap0 = A + (size_t)(bm + (ch0 >> 2)) * K + (ch0 & 3) * 8;
  const u16* ap1 = A + (size_t)(bm + (ch1 >> 2)) * K + (ch1 & 3) * 8;
  const u16* bp0 = Bt + (size_t)(bn + (ch0 >> 2)) * K + (ch0 & 3) * 8;
  const u16* bp1 = Bt + (size_t)(bn + (ch1 >> 2)) * K + (ch1 & 3) * 8;

  uint4 pA0 = *(const uint4*)ap0, pA1 = *(const uint4*)ap1;
  uint4 pB0 = *(const uint4*)bp0, pB1 = *(const uint4*)bp1;

  f4 acc[4][4] = {};
  const int iters = K >> 5;
  for (int it = 0; it < iters; ++it) {
    const int s = it & 1;
    *(uint4*)(lA[s] + ch0 * 8) = pA0; *(uint4*)(lA[s] + ch1 * 8) = pA1;
    *(uint4*)(lB[s] + ch0 * 8) = pB0; *(uint4*)(lB[s] + ch1 * 8) = pB1;
    if (it + 1 < iters) {
      ap0 += 32; ap1 += 32; bp0 += 32; bp1 += 32;
      pA0 = *(const uint4*)ap0; pA1 = *(const uint4*)ap1;
      pB0 = *(const uint4*)bp0; pB1 = *(const uint4*)bp1;
    }
    __syncthreads();
    b8 af[4], bf[4];
#pragma unroll
    for (int i = 0; i < 4; ++i)
      af[i] = *(const b8*)(lA[s] + (wm + i * 16 + lrow) * 32 + lq * 8);
#pragma unroll
    for (int j = 0; j < 4; ++j)
      bf[j] = *(const b8*)(lB[s] + (wn + j * 16 + lrow) * 32 + lq * 8);
#pragma unroll
    for (int i = 0; i < 4; ++i)
#pragma unroll
      for (int j = 0; j < 4; ++j)
        acc[i][j] = __builtin_amdgcn_mfma_f32_16x16x32_bf16(af[i], bf[j], acc[i][j], 0, 0, 0);
  }

  float bv[4];
#pragma unroll
  for (int j = 0; j < 4; ++j) bv[j] = bias[bn + wn + j * 16 + lrow];

  const float CS = 0.125f * 1.44269504088896340736f;  // scale * log2(e), folded into q
  const int n0w = bn + wn;                 // 64-aligned: one head's D-range per wave
  const int sec = n0w >> 10;               // 0=q, 1=k, 2=v (wave-uniform)
  const int h = (n0w >> 6) & 15;
#pragma unroll
  for (int i = 0; i < 4; ++i) {
    float v[4][4];  // [j][r]
#pragma unroll
    for (int j = 0; j < 4; ++j)
#pragma unroll
      for (int r = 0; r < 4; ++r) v[j][r] = acc[i][j][r] + bv[j];
    if (sec < 2) {
      u16* dst = sec == 0 ? oq : ok;
      const float* w = sec == 0 ? qw : kw;
      float ex = sec == 0 ? CS : 1.0f;
#pragma unroll
      for (int r = 0; r < 4; ++r) {
        float ss = v[0][r] * v[0][r] + v[1][r] * v[1][r] +
                   v[2][r] * v[2][r] + v[3][r] * v[3][r];
        ss += __shfl_xor(ss, 1, 64); ss += __shfl_xor(ss, 2, 64);
        ss += __shfl_xor(ss, 4, 64); ss += __shfl_xor(ss, 8, 64);
        float sc = rsqrtf(ss * (1.0f / 64.0f) + 1e-6f) * ex;
        int m = bm + wm + i * 16 + lq * 4 + r;
        int bb = m >> 11, ns = m & 2047;
        u16* rowp = dst + ((size_t)(bb * 16 + h) * 2048 + ns) * 64;
#pragma unroll
        for (int j = 0; j < 4; ++j) {
          int d = j * 16 + lrow;
          rowp[d] = f2bf(v[j][r] * sc * w[d]);
        }
      }
    } else {
      int m0 = bm + wm + i * 16 + lq * 4;
      int bb = m0 >> 11, ns = m0 & 2047;
#pragma unroll
      for (int j = 0; j < 4; ++j) {
        int d = j * 16 + lrow;
        union { _Float16 hh[4]; uint2 u; } pk;
#pragma unroll
        for (int r = 0; r < 4; ++r) pk.hh[r] = (_Float16)v[j][r];
        *(uint2*)(ov + ((size_t)(bb * 16 + h) * 64 + d) * 2048 + ns) = pk.u;
      }
    }
  }
}

// ---- 64x128 bf16 MFMA GEMM for the out-proj, double-buffered, one barrier/iter ----
__global__ __launch_bounds__(256, 4) void k_gemm2(
    const u16* __restrict__ A, const u16* __restrict__ Bt,
    const float* __restrict__ bias, float* __restrict__ outF,
    int K, int Ncols) {
  __shared__ u16 lA[2][64 * 32];
  __shared__ u16 lB[2][128 * 32];
  const int tid = threadIdx.x;
  const int lane = tid & 63, lrow = lane & 15, lq = lane >> 4;
  const int wave = tid >> 6;
  const int bm = blockIdx.y * 64, bn = blockIdx.x * 128;
  const int wm = (wave >> 1) * 32, wn = (wave & 1) * 64;

  const int cha = tid;
  const int ch0 = tid, ch1 = 256 + tid;
  const u16* ap = A + (size_t)(bm + (cha >> 2)) * K + (cha & 3) * 8;
  const u16* bp0 = Bt + (size_t)(bn + (ch0 >> 2)) * K + (ch0 & 3) * 8;
  const u16* bp1 = Bt + (size_t)(bn + (ch1 >> 2)) * K + (ch1 & 3) * 8;

  uint4 pA = *(const uint4*)ap;
  uint4 pB0 = *(const uint4*)bp0, pB1 = *(const uint4*)bp1;

  f4 acc[2][4] = {};
  const int iters = K >> 5;
  for (int it = 0; it < iters; ++it) {
    const int s = it & 1;
    *(uint4*)(lA[s] + cha * 8) = pA;
    *(uint4*)(lB[s] + ch0 * 8) = pB0; *(uint4*)(lB[s] + ch1 * 8) = pB1;
    if (it + 1 < iters) {
      ap += 32; bp0 += 32; bp1 += 32;
      pA = *(const uint4*)ap;
      pB0 = *(const uint4*)bp0; pB1 = *(const uint4*)bp1;
    }
    __syncthreads();
    b8 af[2], bf[4];
#pragma unroll
    for (int i = 0; i < 2; ++i)
      af[i] = *(const b8*)(lA[s] + (wm + i * 16 + lrow) * 32 + lq * 8);
#pragma unroll
    for (int j = 0; j < 4; ++j)
      bf[j] = *(const b8*)(lB[s] + (wn + j * 16 + lrow) * 32 + lq * 8);
#pragma unroll
    for (int i = 0; i < 2; ++i)
#pragma unroll
      for (int j = 0; j < 4; ++j)
        acc[i][j] = __builtin_amdgcn_mfma_f32_16x16x32_bf16(af[i], bf[j], acc[i][j], 0, 0, 0);
  }
#pragma unroll
  for (int i = 0; i < 2; ++i)
#pragma unroll
    for (int j = 0; j < 4; ++j) {
      int n = bn + wn + j * 16 + lrow;
      float bv = bias[n];
#pragma unroll
      for (int r = 0; r < 4; ++r) {
        int m = bm + wm + i * 16 + lq * 4 + r;
        outF[(size_t)m * Ncols + n] = acc[i][j][r] + bv;
      }
    }
}

// -------- flash attention, S^T orientation, 32 q/wave, dbuf single-barrier --------
// R17 delta vs R16: double-buffered LDS, ONE barrier per K-iter. Grid 256 =
// 1 block/CU so LDS 72.7KB is free; 80 VGPR vs 256 budget so dbuf indexing
// cannot spill (R10's failure mode). Halves barrier drains 32->16; fast waves
// run a full iteration ahead. Race-free: no wave reaches store(it+2) into
// buf[s] until all waves passed sync(it+1), i.e. finished compute(it).
// Keeps: dual q-fragments (each kf/va read feeds 2 MFMAs), XCD swizzle
// (bh = b&31: same-head blocks on same XCD; FETCH 12MB measured), no-max
// softmax (|st|<=11.6, p=exp2(st)), VALU lsum.
__global__ __launch_bounds__(512, 2) void k_attn(
    const u16* __restrict__ qb, const u16* __restrict__ kb,
    const u16* __restrict__ vt, u16* __restrict__ ao) {
  __shared__ u16 lK[2][128 * 72];   // [key][d] bf16, stride 72 (9x16B: conflict-free)
  __shared__ u16 lV[2][64 * 140];   // [d][key] f16, stride 140 (35 8B-granules, odd)
  const int b = blockIdx.x;
  const int bh = b & 31;          // XCD swizzle: same-bh blocks == same id mod 8
  const int q0 = (b >> 5) * 256;
  const int tid = threadIdx.x, wave = tid >> 6, lane = tid & 63;
  const int lrow = lane & 15, lq = lane >> 4;
  const int wq = wave * 32;

  // Q fragments, two 16-q groups (B-operand: n=q=lane&15, k=d=quad*8+j); CS pre-folded
  b8 qf[2][2];
#pragma unroll
  for (int g = 0; g < 2; ++g)
#pragma unroll
    for (int ks = 0; ks < 2; ++ks)
      qf[g][ks] = *(const b8*)(qb + ((size_t)bh * 2048 + q0 + wq + g * 16 + lrow) * 64 +
                               ks * 32 + lq * 8);

  f4 o[2][4] = {};     // O^T partials [g][dt]: row=d=quad*4+r, col=q=lane&15
  f4 lsum[2] = {};     // deferred l partials (VALU; reduced once at the end)

  // staging: K tile 128x64 = 1024 chunks + V tile 64x128 = 1024; 4/thread
  const int ch0 = tid, ch1 = 512 + tid;
  const u16* kp0 = kb + (size_t)bh * 2048 * 64 + (size_t)(ch0 >> 3) * 64 + (ch0 & 7) * 8;
  const u16* kp1 = kb + (size_t)bh * 2048 * 64 + (size_t)(ch1 >> 3) * 64 + (ch1 & 7) * 8;
  const u16* vp0 = vt + (size_t)bh * 64 * 2048 + (size_t)(ch0 >> 4) * 2048 + (ch0 & 15) * 8;
  const u16* vp1 = vt + (size_t)bh * 64 * 2048 + (size_t)(ch1 >> 4) * 2048 + (ch1 & 15) * 8;
  const int kO0 = (ch0 >> 3) * 72 + (ch0 & 7) * 8;
  const int kO1 = (ch1 >> 3) * 72 + (ch1 & 7) * 8;
  const int vO0 = (ch0 >> 4) * 140 + (ch0 & 15) * 8;
  const int vO1 = (ch1 >> 4) * 140 + (ch1 & 15) * 8;

  uint4 pK0 = *(const uint4*)kp0, pK1 = *(const uint4*)kp1;
  uint4 pV0 = *(const uint4*)vp0, pV1 = *(const uint4*)vp1;

  for (int it = 0; it < 16; ++it) {
    const int s = it & 1;
    // store prefetched tile regs -> LDS buf[s]
    *(uint4*)(lK[s] + kO0) = pK0;
    *(uint4*)(lK[s] + kO1) = pK1;
    *(uint2*)(lV[s] + vO0) = make_uint2(pV0.x, pV0.y);     // 280B rows not 16B-aligned
    *(uint2*)(lV[s] + vO0 + 4) = make_uint2(pV0.z, pV0.w);
    *(uint2*)(lV[s] + vO1) = make_uint2(pV1.x, pV1.y);
    *(uint2*)(lV[s] + vO1 + 4) = make_uint2(pV1.z, pV1.w);

    // issue next tile's global loads; they drain during the compute below
    if (it < 15) {
      kp0 += 128 * 64; kp1 += 128 * 64; vp0 += 128; vp1 += 128;
      pK0 = *(const uint4*)kp0; pK1 = *(const uint4*)kp1;
      pV0 = *(const uint4*)vp0; pV1 = *(const uint4*)vp1;
    }
    __syncthreads();   // single barrier: buf[s] visible; buf[s^1] free for next store

    // ST = K·Q^T for both q groups: each kf read feeds 2 MFMAs
    f4 st[2][8] = {};
#pragma unroll
    for (int ks = 0; ks < 2; ++ks)
#pragma unroll
      for (int kt = 0; kt < 8; ++kt) {
        b8 kf = *(const b8*)(lK[s] + (kt * 16 + lrow) * 72 + ks * 32 + lq * 8);
        st[0][kt] = __builtin_amdgcn_mfma_f32_16x16x32_bf16(kf, qf[0][ks], st[0][kt], 0, 0, 0);
        st[1][kt] = __builtin_amdgcn_mfma_f32_16x16x32_bf16(kf, qf[1][ks], st[1][kt], 0, 0, 0);
      }

    // p = exp2(st): raw v_exp_f32 (bounded inputs); l accumulates on VALU
    h4 pf[2][8];
#pragma unroll
    for (int g = 0; g < 2; ++g)
#pragma unroll
      for (int kt = 0; kt < 8; ++kt) {
        f4 e;
#pragma unroll
        for (int r = 0; r < 4; ++r) e[r] = EXP2(st[g][kt][r]);
        lsum[g] += e;
        union { hp2 p2[2]; h4 v; } cv;
        cv.p2[0] = __builtin_amdgcn_cvt_pkrtz(e[0], e[1]);
        cv.p2[1] = __builtin_amdgcn_cvt_pkrtz(e[2], e[3]);
        pf[g][kt] = cv.v;
      }

    // O^T += V^T·P^T — each va read feeds 2 MFMAs
#pragma unroll
    for (int kt = 0; kt < 8; ++kt) {
#pragma unroll
      for (int dt = 0; dt < 4; ++dt) {
        h4 va = *(const h4*)(lV[s] + (dt * 16 + lrow) * 140 + kt * 16 + lq * 4);
        o[0][dt] = __builtin_amdgcn_mfma_f32_16x16x16f16(va, pf[0][kt], o[0][dt], 0, 0, 0);
        o[1][dt] = __builtin_amdgcn_mfma_f32_16x16x16f16(va, pf[1][kt], o[1][dt], 0, 0, 0);
      }
    }
  }

  const int bb = bh >> 4, h = bh & 15;
#pragma unroll
  for (int g = 0; g < 2; ++g) {
    // final l reduction: 4 regs + 2 shuffles across the 4 quads
    float l = lsum[g][0] + lsum[g][1] + lsum[g][2] + lsum[g][3];
    l += __shfl_xor(l, 16, 64);
    l += __shfl_xor(l, 32, 64);
    float inv = 1.0f / l;
    int q = q0 + wq + g * 16 + lrow;
#pragma unroll
    for (int dt = 0; dt < 4; ++dt) {
      union { u16 h2[4]; uint2 v; } r;
#pragma unroll
      for (int rr = 0; rr < 4; ++rr) r.h2[rr] = f2bf(o[g][dt][rr] * inv);
      *(uint2*)(ao + ((size_t)bb * 2048 + q) * 1024 + h * 64 + dt * 16 + lq * 4) = r.v;
    }
  }
}

extern "C" void kernel_launch(void* const* d_in, const int* in_sizes, int n_in,
                              void* d_out, int out_size, void* d_ws, size_t ws_size,
                              hipStream_t stream) {
  const float* x      = (const float*)d_in[0];
  const float* w_qkv  = (const float*)d_in[1];
  const float* b_qkv  = (const float*)d_in[2];
  const float* q_w    = (const float*)d_in[3];
  const float* k_w    = (const float*)d_in[4];
  const float* w_proj = (const float*)d_in[5];
  const float* b_proj = (const float*)d_in[6];
  float* out = (float*)d_out;

  u16* xb   = (u16*)d_ws;          // 4096x1024 bf16
  u16* wqkT = xb + 4194304;        // 3072x1024 bf16
  u16* wpjT = wqkT + 3145728;      // 1024x1024 bf16
  u16* qb   = wpjT + 1048576;      // [BH][N][D] bf16 (CS-scaled)
  u16* kb   = qb + 4194304;        // [BH][N][D] bf16
  u16* vtb  = kb + 4194304;        // [BH][D][N] f16
  u16* ao   = xb;                  // attention out reuses xb

  k_convert_all<<<3072, 256, 0, stream>>>(x, w_qkv, w_proj, xb, wqkT, wpjT);
  k_gemm_qkv<<<dim3(24, 32), 256, 0, stream>>>(xb, wqkT, b_qkv, qb, kb, vtb, q_w, k_w, 1024);
  k_attn<<<256, 512, 0, stream>>>(qb, kb, vtb, ao);
  k_gemm2<<<dim3(8, 64), 256, 0, stream>>>(ao, wpjT, b_proj, out, 1024, 1024);
}